// Round 6
// baseline (2287.354 us; speedup 1.0000x reference)
//
#include <hip/hip_runtime.h>

// HeteroGNN: 2 layers x 4 GATConv (single head), N=100000, E=800000, C=128.
// R6: (1) MFMA bf16 GEMM (16x16x32, f32 accum) with pre-transposed bf16 W;
//     layer-1 agg output stored bf16 so layer-2 GEMM reads bf16 directly.
//     (2) agg restructured: 16-lane group per node (4 nodes/wave), shfl-free
//     broadcast edge scores, 8 feats/lane, 4-wide unroll -> 16 gathers/wave.

#define NEG_SLOPE 0.2f

typedef __attribute__((ext_vector_type(8))) short short8v;
typedef __attribute__((ext_vector_type(4))) float float4v;

__device__ __forceinline__ unsigned short f2bf(float f) {
  unsigned u = __float_as_uint(f);
  unsigned r = (u + 0x7FFFu + ((u >> 16) & 1u)) >> 16;
  return (unsigned short)r;
}
__device__ __forceinline__ unsigned pack2(float a, float b) {
  return (unsigned)f2bf(a) | ((unsigned)f2bf(b) << 16);
}
__device__ __forceinline__ float bflo(unsigned u) {
  return __uint_as_float(u << 16);
}
__device__ __forceinline__ float bfhi(unsigned u) {
  return __uint_as_float(u & 0xFFFF0000u);
}

// ---------- W -> bf16 transposed (Wt[n][k] = W[k][n]), 8 matrices ----------
__global__ __launch_bounds__(256) void w_to_bf16t(const float* __restrict__ W,
                                                  unsigned short* __restrict__ Wt) {
  __shared__ float buf[64][129];
  int b = blockIdx.x, t = threadIdx.x;
  const float* w = W + (size_t)b * 16384;
  unsigned short* o = Wt + (size_t)b * 16384;
  for (int h = 0; h < 2; ++h) {
    for (int i = 0; i < 32; ++i) {
      int idx = i * 256 + t;            // 8192 elements: k' = idx>>7, n = idx&127
      buf[idx >> 7][idx & 127] = w[(size_t)(h * 64 + (idx >> 7)) * 128 + (idx & 127)];
    }
    __syncthreads();
    for (int i = 0; i < 32; ++i) {
      int idx = i * 256 + t;            // out: n = idx>>6, k' = idx&63
      o[(size_t)(idx >> 6) * 128 + h * 64 + (idx & 63)] = f2bf(buf[idx & 63][idx >> 6]);
    }
    __syncthreads();
  }
}

// ---------- precompute (Wd @ a_d) for all 8 (layer,conv) ----------
__global__ void precompute_wa(const float* __restrict__ W,
                              const float* __restrict__ att,
                              float* __restrict__ out) {
  int idx = blockIdx.x;   // 0..7
  int f = threadIdx.x;    // 0..127
  const float* w = W + (size_t)idx * 128 * 128 + (size_t)f * 128;
  const float* a = att + idx * 128;
  float s = 0.f;
  #pragma unroll 8
  for (int h = 0; h < 128; ++h) s += w[h] * a[h];
  out[idx * 128 + f] = s;
}

// ---------- MFMA dual GEMM: Hb1 = X@W1, Hb2 = X@W2 (bf16 out, f32 accum) ----
// as1/as2 = rowsum(acc*att) epilogues; adA/adB = X.vdA / X.vdB.
// Tile: 64 rows x 128 cols, 4 waves (16 rows each), K = 128 = 4 x 32.
template <int XBF16>
__global__ __launch_bounds__(256) void gemm_dual(
    const void* __restrict__ Xv,
    const unsigned short* __restrict__ Wt1, const float* __restrict__ att1,
    unsigned short* __restrict__ Hb1, float* __restrict__ as1,
    const unsigned short* __restrict__ Wt2, const float* __restrict__ att2,
    unsigned short* __restrict__ Hb2, float* __restrict__ as2,
    const float* __restrict__ vdA, const float* __restrict__ vdB,
    float* __restrict__ adA, float* __restrict__ adB, int M) {
  __shared__ unsigned short Xt[64][136];    // [row][k], bf16, padded
  __shared__ unsigned short Wt[128][136];   // [n][k], bf16, padded
  const int t = threadIdx.x;
  const int row0 = blockIdx.x * 64;

  // stage X tile as bf16
  {
    int r = t >> 2;
    int cq = (t & 3) * 32;
    int gr = row0 + r;
    if (gr >= M) gr = M - 1;
    if (XBF16) {
      const unsigned short* Xb = (const unsigned short*)Xv;
      const uint4* src = (const uint4*)(Xb + (size_t)gr * 128 + cq);
      #pragma unroll
      for (int i = 0; i < 4; ++i) *(uint4*)&Xt[r][cq + i * 8] = src[i];
    } else {
      const float* Xf = (const float*)Xv;
      const float4* src = (const float4*)(Xf + (size_t)gr * 128 + cq);
      #pragma unroll
      for (int i = 0; i < 8; ++i) {
        float4 v = src[i];
        uint2 u;
        u.x = pack2(v.x, v.y);
        u.y = pack2(v.z, v.w);
        *(uint2*)&Xt[r][cq + i * 4] = u;
      }
    }
  }
  // stage W1
  {
    int n = t >> 1;
    int kh = (t & 1) * 64;
    const uint4* src = (const uint4*)(Wt1 + (size_t)n * 128 + kh);
    #pragma unroll
    for (int i = 0; i < 8; ++i) *(uint4*)&Wt[n][kh + i * 8] = src[i];
  }
  __syncthreads();

  // ad epilogue: rows 0..63 dot vdA (threads 0-63) / vdB (threads 64-127)
  if (t < 128) {
    int r = t & 63;
    const float* vd = (t < 64) ? vdA : vdB;
    float* adout = (t < 64) ? adA : adB;
    float sum = 0.f;
    #pragma unroll 4
    for (int k8 = 0; k8 < 16; ++k8) {
      uint4 u = *(const uint4*)&Xt[r][k8 * 8];
      const float* v = vd + k8 * 8;
      sum = fmaf(bflo(u.x), v[0], sum);
      sum = fmaf(bfhi(u.x), v[1], sum);
      sum = fmaf(bflo(u.y), v[2], sum);
      sum = fmaf(bfhi(u.y), v[3], sum);
      sum = fmaf(bflo(u.z), v[4], sum);
      sum = fmaf(bfhi(u.z), v[5], sum);
      sum = fmaf(bflo(u.w), v[6], sum);
      sum = fmaf(bfhi(u.w), v[7], sum);
    }
    int gr = row0 + r;
    if (gr < M) adout[gr] = sum;
  }

  const int lane = t & 63;
  const int wv = t >> 6;          // wave 0..3 -> rows ws..ws+15
  const int m = lane & 15;        // A-row / B-col / D-col
  const int g = lane >> 4;        // k-chunk group; D-rows g*4..g*4+3
  const int ws = wv * 16;

  for (int ww = 0; ww < 2; ++ww) {
    if (ww == 1) {
      __syncthreads();            // everyone done with W1
      int n = t >> 1;
      int kh = (t & 1) * 64;
      const uint4* src = (const uint4*)(Wt2 + (size_t)n * 128 + kh);
      #pragma unroll
      for (int i = 0; i < 8; ++i) *(uint4*)&Wt[n][kh + i * 8] = src[i];
      __syncthreads();
    }
    const float* att = ww ? att2 : att1;
    unsigned short* Hb = ww ? Hb2 : Hb1;
    float* as_ = ww ? as2 : as1;

    float4v acc[8];
    float4v z = {0.f, 0.f, 0.f, 0.f};
    #pragma unroll
    for (int nt = 0; nt < 8; ++nt) acc[nt] = z;

    #pragma unroll
    for (int ks = 0; ks < 4; ++ks) {
      short8v a = *(const short8v*)&Xt[ws + m][ks * 32 + g * 8];
      #pragma unroll
      for (int nt = 0; nt < 8; ++nt) {
        short8v b = *(const short8v*)&Wt[nt * 16 + m][ks * 32 + g * 8];
        acc[nt] = __builtin_amdgcn_mfma_f32_16x16x32_bf16(a, b, acc[nt], 0, 0, 0);
      }
    }

    // as epilogue: as[row] = sum_col acc[row][col]*att[col]
    {
      float attv[8];
      #pragma unroll
      for (int nt = 0; nt < 8; ++nt) attv[nt] = att[nt * 16 + m];
      #pragma unroll
      for (int r = 0; r < 4; ++r) {
        float s = 0.f;
        #pragma unroll
        for (int nt = 0; nt < 8; ++nt) s = fmaf(acc[nt][r], attv[nt], s);
        #pragma unroll
        for (int off = 1; off < 16; off <<= 1) s += __shfl_xor(s, off);
        if (m == 0) {
          int grow = row0 + ws + g * 4 + r;
          if (grow < M) as_[grow] = s;
        }
      }
    }

    // hs store: bf16, pack adjacent-col pairs via lane shuffle
    #pragma unroll
    for (int nt = 0; nt < 8; ++nt) {
      #pragma unroll
      for (int r = 0; r < 4; ++r) {
        float v = acc[nt][r];
        float vn = __shfl_xor(v, 1);
        if ((m & 1) == 0) {
          int grow = row0 + ws + g * 4 + r;
          if (grow < M) {
            *(unsigned*)(Hb + (size_t)grow * 128 + nt * 16 + m) = pack2(v, vn);
          }
        }
      }
    }
  }
}

// ---------- CSR build ----------
__global__ void hist4(const int* __restrict__ e0, const int* __restrict__ e1,
                      const int* __restrict__ e2, const int* __restrict__ e3,
                      int E, int* __restrict__ deg, int N) {
  int i = blockIdx.x * 256 + threadIdx.x;
  if (i >= E) return;
  int t = blockIdx.y;
  const int* ei = (t == 0) ? e0 : (t == 1) ? e1 : (t == 2) ? e2 : e3;
  atomicAdd(&deg[t * N + ei[E + i]], 1);
}

__global__ __launch_bounds__(1024) void scan4(const int* __restrict__ deg,
                                              int* __restrict__ rowptr, int N) {
  __shared__ int sums[1024];
  int t = threadIdx.x;
  int ty = blockIdx.x;
  const int* d = deg + (size_t)ty * N;
  int* rp = rowptr + (size_t)ty * (N + 1);
  int chunk = (N + 1023) / 1024;
  int lo = t * chunk;
  int hi = lo + chunk; if (hi > N) hi = N; if (lo > N) lo = N;
  int s = 0;
  for (int i = lo; i < hi; ++i) s += d[i];
  sums[t] = s;
  __syncthreads();
  for (int off = 1; off < 1024; off <<= 1) {
    int add = (t >= off) ? sums[t - off] : 0;
    __syncthreads();
    sums[t] += add;
    __syncthreads();
  }
  int run = (t == 0) ? 0 : sums[t - 1];
  for (int i = lo; i < hi; ++i) {
    rp[i] = run;
    run += d[i];
  }
  if (t == 1023) rp[N] = sums[1023];
}

__global__ void fill4(const int* __restrict__ e0, const int* __restrict__ e1,
                      const int* __restrict__ e2, const int* __restrict__ e3,
                      int E, const int* __restrict__ rowptr,
                      int* __restrict__ fill, int* __restrict__ csrc, int N) {
  int i = blockIdx.x * 256 + threadIdx.x;
  if (i >= E) return;
  int t = blockIdx.y;
  const int* ei = (t == 0) ? e0 : (t == 1) ? e1 : (t == 2) ? e2 : e3;
  int d = ei[E + i];
  int s = ei[i];
  int pos = rowptr[(size_t)t * (N + 1) + d] + atomicAdd(&fill[t * N + d], 1);
  csrc[(size_t)t * E + pos] = s;
}

// ---------- agg: 16-lane group per node, shfl-free, 8 feats/lane ----------
#define ACC8(p, h) {                                      \
  acc[0] = fmaf(p, bflo((h).x), acc[0]);                  \
  acc[1] = fmaf(p, bfhi((h).x), acc[1]);                  \
  acc[2] = fmaf(p, bflo((h).y), acc[2]);                  \
  acc[3] = fmaf(p, bfhi((h).y), acc[3]);                  \
  acc[4] = fmaf(p, bflo((h).z), acc[4]);                  \
  acc[5] = fmaf(p, bfhi((h).z), acc[5]);                  \
  acc[6] = fmaf(p, bflo((h).w), acc[6]);                  \
  acc[7] = fmaf(p, bfhi((h).w), acc[7]); }

__device__ __forceinline__ void agg16(const int* __restrict__ rowptr,
                                      const int* __restrict__ csrc,
                                      const unsigned short* __restrict__ hs,
                                      const float* __restrict__ as_, float ad,
                                      int node, int q, float* acc) {
  int beg = rowptr[node], end = rowptr[node + 1];
  float lsum = 0.f;
  #pragma unroll
  for (int i = 0; i < 8; ++i) acc[i] = 0.f;
  int c = beg;
  for (; c + 3 < end; c += 4) {
    int s0 = csrc[c + 0], s1 = csrc[c + 1], s2 = csrc[c + 2], s3 = csrc[c + 3];
    uint4 h0 = *(const uint4*)(hs + (size_t)s0 * 128 + q * 8);
    uint4 h1 = *(const uint4*)(hs + (size_t)s1 * 128 + q * 8);
    uint4 h2 = *(const uint4*)(hs + (size_t)s2 * 128 + q * 8);
    uint4 h3 = *(const uint4*)(hs + (size_t)s3 * 128 + q * 8);
    float e0 = as_[s0] + ad, e1 = as_[s1] + ad;
    float e2 = as_[s2] + ad, e3 = as_[s3] + ad;
    e0 = e0 > 0.f ? e0 : NEG_SLOPE * e0;
    e1 = e1 > 0.f ? e1 : NEG_SLOPE * e1;
    e2 = e2 > 0.f ? e2 : NEG_SLOPE * e2;
    e3 = e3 > 0.f ? e3 : NEG_SLOPE * e3;
    float p0 = __expf(e0), p1 = __expf(e1), p2 = __expf(e2), p3 = __expf(e3);
    lsum += (p0 + p1) + (p2 + p3);
    ACC8(p0, h0) ACC8(p1, h1) ACC8(p2, h2) ACC8(p3, h3)
  }
  for (; c < end; ++c) {
    int s0 = csrc[c];
    uint4 h0 = *(const uint4*)(hs + (size_t)s0 * 128 + q * 8);
    float e0 = as_[s0] + ad;
    e0 = e0 > 0.f ? e0 : NEG_SLOPE * e0;
    float p0 = __expf(e0);
    lsum += p0;
    ACC8(p0, h0)
  }
  float inv = 1.f / fmaxf(lsum, 1e-16f);
  #pragma unroll
  for (int i = 0; i < 8; ++i) acc[i] *= inv;
}

// ---------- fused: out[n] = bf16(tanh(aggA + aggB + biasA + biasB)) ----------
__global__ __launch_bounds__(256) void fused_agg_store(
    const int* __restrict__ rA, const int* __restrict__ sA,
    const unsigned short* __restrict__ hA, const float* __restrict__ asA,
    const float* __restrict__ adA, const int* __restrict__ rB,
    const int* __restrict__ sB, const unsigned short* __restrict__ hB,
    const float* __restrict__ asB, const float* __restrict__ adB,
    const float* __restrict__ biasA, const float* __restrict__ biasB,
    unsigned short* __restrict__ out, int N) {
  int node = blockIdx.x * 16 + (threadIdx.x >> 4);
  int q = threadIdx.x & 15;
  if (node >= N) return;
  float accA[8], accB[8];
  agg16(rA, sA, hA, asA, adA[node], node, q, accA);
  agg16(rB, sB, hB, asB, adB[node], node, q, accB);
  float4 ba0 = *(const float4*)(biasA + q * 8);
  float4 ba1 = *(const float4*)(biasA + q * 8 + 4);
  float4 bb0 = *(const float4*)(biasB + q * 8);
  float4 bb1 = *(const float4*)(biasB + q * 8 + 4);
  float v[8];
  v[0] = tanhf(accA[0] + accB[0] + ba0.x + bb0.x);
  v[1] = tanhf(accA[1] + accB[1] + ba0.y + bb0.y);
  v[2] = tanhf(accA[2] + accB[2] + ba0.z + bb0.z);
  v[3] = tanhf(accA[3] + accB[3] + ba0.w + bb0.w);
  v[4] = tanhf(accA[4] + accB[4] + ba1.x + bb1.x);
  v[5] = tanhf(accA[5] + accB[5] + ba1.y + bb1.y);
  v[6] = tanhf(accA[6] + accB[6] + ba1.z + bb1.z);
  v[7] = tanhf(accA[7] + accB[7] + ba1.w + bb1.w);
  uint4 o;
  o.x = pack2(v[0], v[1]);
  o.y = pack2(v[2], v[3]);
  o.z = pack2(v[4], v[5]);
  o.w = pack2(v[6], v[7]);
  *(uint4*)(out + (size_t)node * 128 + q * 8) = o;
}

// ---------- fused layer-2: tanh(...) pooled directly (atomic) ----------
__global__ __launch_bounds__(256) void fused_agg_pool(
    const int* __restrict__ rA, const int* __restrict__ sA,
    const unsigned short* __restrict__ hA, const float* __restrict__ asA,
    const float* __restrict__ adA, const int* __restrict__ rB,
    const int* __restrict__ sB, const unsigned short* __restrict__ hB,
    const float* __restrict__ asB, const float* __restrict__ adB,
    const float* __restrict__ biasA, const float* __restrict__ biasB,
    const int* __restrict__ batch, float* __restrict__ pool, int N) {
  int node = blockIdx.x * 16 + (threadIdx.x >> 4);
  int q = threadIdx.x & 15;
  if (node >= N) return;
  float accA[8], accB[8];
  agg16(rA, sA, hA, asA, adA[node], node, q, accA);
  agg16(rB, sB, hB, asB, adB[node], node, q, accB);
  float4 ba0 = *(const float4*)(biasA + q * 8);
  float4 ba1 = *(const float4*)(biasA + q * 8 + 4);
  float4 bb0 = *(const float4*)(biasB + q * 8);
  float4 bb1 = *(const float4*)(biasB + q * 8 + 4);
  int bb = batch[node];
  float* p = pool + (size_t)bb * 128 + q * 8;
  unsafeAtomicAdd(p + 0, tanhf(accA[0] + accB[0] + ba0.x + bb0.x));
  unsafeAtomicAdd(p + 1, tanhf(accA[1] + accB[1] + ba0.y + bb0.y));
  unsafeAtomicAdd(p + 2, tanhf(accA[2] + accB[2] + ba0.z + bb0.z));
  unsafeAtomicAdd(p + 3, tanhf(accA[3] + accB[3] + ba0.w + bb0.w));
  unsafeAtomicAdd(p + 4, tanhf(accA[4] + accB[4] + ba1.x + bb1.x));
  unsafeAtomicAdd(p + 5, tanhf(accA[5] + accB[5] + ba1.y + bb1.y));
  unsafeAtomicAdd(p + 6, tanhf(accA[6] + accB[6] + ba1.z + bb1.z));
  unsafeAtomicAdd(p + 7, tanhf(accA[7] + accB[7] + ba1.w + bb1.w));
}

// ---------- batch count histogram ----------
__global__ void batch_hist(const int* __restrict__ batch,
                           float* __restrict__ cnt, int N) {
  int i = blockIdx.x * 256 + threadIdx.x;
  if (i >= N) return;
  atomicAdd(&cnt[batch[i]], 1.0f);
}

// ---------- final ----------
__global__ void final_k(const float* __restrict__ pool_i,
                        const float* __restrict__ cnt_i,
                        const float* __restrict__ pool_j,
                        const float* __restrict__ cnt_j,
                        const float* __restrict__ lin_w,
                        const float* __restrict__ lin_b,
                        float* __restrict__ out) {
  int b = threadIdx.x;  // 256
  float ci = fmaxf(cnt_i[b], 1.f);
  float cj = fmaxf(cnt_j[b], 1.f);
  float acc = 0.f;
  #pragma unroll 4
  for (int f = 0; f < 128; ++f) {
    float x = 0.5f * (pool_i[(size_t)b * 128 + f] / ci +
                      pool_j[(size_t)b * 128 + f] / cj);
    acc += x * lin_w[f];
  }
  acc += lin_b[0];
  out[b] = 1.f / (1.f + __expf(-acc));
}

extern "C" void kernel_launch(void* const* d_in, const int* in_sizes, int n_in,
                              void* d_out, int out_size, void* d_ws,
                              size_t ws_size, hipStream_t stream) {
  const float* x_i = (const float*)d_in[0];
  const float* x_j = (const float*)d_in[1];
  const int* ei_arr[4] = {(const int*)d_in[2], (const int*)d_in[3],
                          (const int*)d_in[4], (const int*)d_in[5]};  // ii,jj,ij,ji
  const int* batch_i = (const int*)d_in[6];
  const int* batch_j = (const int*)d_in[7];
  const float* Ws = (const float*)d_in[8];
  const float* Wd = (const float*)d_in[9];
  const float* att_s = (const float*)d_in[10];
  const float* att_d = (const float*)d_in[11];
  const float* bias = (const float*)d_in[12];
  const float* lin_w = (const float*)d_in[13];
  const float* lin_b = (const float*)d_in[14];
  float* out = (float*)d_out;

  const int N = in_sizes[0] / 128;   // 100000
  const int E = in_sizes[2] / 2;     // 800000
  const size_t NF = (size_t)N * 128;

  char* w = (char*)d_ws;
  auto alloc = [&](size_t bytes) {
    char* p = w;
    w += (bytes + 255) & ~(size_t)255;
    return p;
  };
  unsigned short* bufA_i = (unsigned short*)alloc(NF * 2);
  unsigned short* bufA_j = (unsigned short*)alloc(NF * 2);
  unsigned short* hsb[4];
  for (int c = 0; c < 4; ++c) hsb[c] = (unsigned short*)alloc(NF * 2);
  int* csrc = (int*)alloc((size_t)4 * E * 4);
  int* rowptr = (int*)alloc((size_t)4 * (N + 1) * 4);
  int* deg = (int*)alloc((size_t)4 * N * 4);
  int* fillc = (int*)alloc((size_t)4 * N * 4);
  float* asb[4];
  for (int c = 0; c < 4; ++c) asb[c] = (float*)alloc((size_t)N * 4);
  float* adb[4];
  for (int c = 0; c < 4; ++c) adb[c] = (float*)alloc((size_t)N * 4);
  float* wdad = (float*)alloc(8 * 128 * 4);
  unsigned short* Wst = (unsigned short*)alloc(8 * 16384 * 2);
  float* pool = (float*)alloc(2 * 256 * 128 * 4);
  float* cnt = (float*)alloc(2 * 256 * 4);
  float* pool_i = pool;
  float* pool_j = pool + 256 * 128;
  float* cnt_i = cnt;
  float* cnt_j = cnt + 256;

  // ---- one-time prep ----
  w_to_bf16t<<<8, 256, 0, stream>>>(Ws, Wst);
  precompute_wa<<<8, 128, 0, stream>>>(Wd, att_d, wdad);

  // ---- CSR build (edge lists shared by both layers) ----
  hipMemsetAsync(deg, 0, (size_t)4 * N * 4, stream);
  hipMemsetAsync(fillc, 0, (size_t)4 * N * 4, stream);
  dim3 egrid((E + 255) / 256, 4);
  hist4<<<egrid, 256, 0, stream>>>(ei_arr[0], ei_arr[1], ei_arr[2], ei_arr[3],
                                   E, deg, N);
  scan4<<<4, 1024, 0, stream>>>(deg, rowptr, N);
  fill4<<<egrid, 256, 0, stream>>>(ei_arr[0], ei_arr[1], ei_arr[2], ei_arr[3],
                                   E, rowptr, fillc, csrc, N);

  hipMemsetAsync(pool, 0, 2 * 256 * 128 * 4, stream);
  hipMemsetAsync(cnt, 0, 2 * 256 * 4, stream);
  batch_hist<<<(N + 255) / 256, 256, 0, stream>>>(batch_i, cnt_i, N);
  batch_hist<<<(N + 255) / 256, 256, 0, stream>>>(batch_j, cnt_j, N);

  const int gemm_blocks = (N + 63) / 64;
  const int agg_blocks = (N + 15) / 16;

  // conv c0 = ii (src i, dst i); c1 = jj (src j, dst j);
  // conv c2 = ij (src i, dst j); c3 = ji (src j, dst i).
  // out_i <- aggregate convs {c0, c3}; out_j <- {c1, c2}.
  for (int l = 0; l < 2; ++l) {
    const void* cur_i = (l == 0) ? (const void*)x_i : (const void*)bufA_i;
    const void* cur_j = (l == 0) ? (const void*)x_j : (const void*)bufA_j;
    const size_t L = (size_t)l * 4;

    // x_i feeds hs/as for convs {0,2} (src=i) and ad for convs {0,3} (dst=i)
    // x_j feeds hs/as for convs {1,3} (src=j) and ad for convs {1,2} (dst=j)
    if (l == 0) {
      gemm_dual<0><<<gemm_blocks, 256, 0, stream>>>(
          cur_i, Wst + (L + 0) * 16384, att_s + (L + 0) * 128, hsb[0], asb[0],
          Wst + (L + 2) * 16384, att_s + (L + 2) * 128, hsb[2], asb[2],
          wdad + (L + 0) * 128, wdad + (L + 3) * 128, adb[0], adb[3], N);
      gemm_dual<0><<<gemm_blocks, 256, 0, stream>>>(
          cur_j, Wst + (L + 1) * 16384, att_s + (L + 1) * 128, hsb[1], asb[1],
          Wst + (L + 3) * 16384, att_s + (L + 3) * 128, hsb[3], asb[3],
          wdad + (L + 1) * 128, wdad + (L + 2) * 128, adb[1], adb[2], N);
    } else {
      gemm_dual<1><<<gemm_blocks, 256, 0, stream>>>(
          cur_i, Wst + (L + 0) * 16384, att_s + (L + 0) * 128, hsb[0], asb[0],
          Wst + (L + 2) * 16384, att_s + (L + 2) * 128, hsb[2], asb[2],
          wdad + (L + 0) * 128, wdad + (L + 3) * 128, adb[0], adb[3], N);
      gemm_dual<1><<<gemm_blocks, 256, 0, stream>>>(
          cur_j, Wst + (L + 1) * 16384, att_s + (L + 1) * 128, hsb[1], asb[1],
          Wst + (L + 3) * 16384, att_s + (L + 3) * 128, hsb[3], asb[3],
          wdad + (L + 1) * 128, wdad + (L + 2) * 128, adb[1], adb[2], N);
    }

    for (int pair = 0; pair < 2; ++pair) {
      int cA = (pair == 0) ? 0 : 1;
      int cB = (pair == 0) ? 3 : 2;
      const int* rA = rowptr + (size_t)cA * (N + 1);
      const int* rB = rowptr + (size_t)cB * (N + 1);
      const int* sA = csrc + (size_t)cA * E;
      const int* sB = csrc + (size_t)cB * E;
      const float* bA = bias + (L + cA) * 128;
      const float* bB = bias + (L + cB) * 128;
      if (l == 0) {
        unsigned short* outb = (pair == 0) ? bufA_i : bufA_j;
        fused_agg_store<<<agg_blocks, 256, 0, stream>>>(
            rA, sA, hsb[cA], asb[cA], adb[cA], rB, sB, hsb[cB], asb[cB],
            adb[cB], bA, bB, outb, N);
      } else {
        const int* batch = (pair == 0) ? batch_i : batch_j;
        float* poolp = (pair == 0) ? pool_i : pool_j;
        fused_agg_pool<<<agg_blocks, 256, 0, stream>>>(
            rA, sA, hsb[cA], asb[cA], adb[cA], rB, sB, hsb[cB], asb[cB],
            adb[cB], bA, bB, batch, poolp, N);
      }
    }
  }

  final_k<<<1, 256, 0, stream>>>(pool_i, cnt_i, pool_j, cnt_j, lin_w, lin_b,
                                 out);
}

// Round 7
// 1534.392 us; speedup vs baseline: 1.4907x; 1.4907x over previous
//
#include <hip/hip_runtime.h>

// HeteroGNN: 2 layers x 4 GATConv (single head), N=100000, E=800000, C=128.
// R7: MFMA bf16 gemm_dual (R6, verified absmax 0.0) + R5's proven agg
// structure (one wave per node, 2 feats/lane, shfl-broadcast edges,
// contiguous float2 pool atomics), gather batched 8-wide for MLP.
// R6's 16-lane-group agg reverted (atomic write amplification + divergence).

#define NEG_SLOPE 0.2f

typedef __attribute__((ext_vector_type(8))) short short8v;
typedef __attribute__((ext_vector_type(4))) float float4v;

__device__ __forceinline__ unsigned short f2bf(float f) {
  unsigned u = __float_as_uint(f);
  unsigned r = (u + 0x7FFFu + ((u >> 16) & 1u)) >> 16;
  return (unsigned short)r;
}
__device__ __forceinline__ unsigned pack2(float a, float b) {
  return (unsigned)f2bf(a) | ((unsigned)f2bf(b) << 16);
}
__device__ __forceinline__ float bflo(unsigned u) {
  return __uint_as_float(u << 16);
}
__device__ __forceinline__ float bfhi(unsigned u) {
  return __uint_as_float(u & 0xFFFF0000u);
}

// ---------- W -> bf16 transposed (Wt[n][k] = W[k][n]), 8 matrices ----------
__global__ __launch_bounds__(256) void w_to_bf16t(const float* __restrict__ W,
                                                  unsigned short* __restrict__ Wt) {
  __shared__ float buf[64][129];
  int b = blockIdx.x, t = threadIdx.x;
  const float* w = W + (size_t)b * 16384;
  unsigned short* o = Wt + (size_t)b * 16384;
  for (int h = 0; h < 2; ++h) {
    for (int i = 0; i < 32; ++i) {
      int idx = i * 256 + t;
      buf[idx >> 7][idx & 127] = w[(size_t)(h * 64 + (idx >> 7)) * 128 + (idx & 127)];
    }
    __syncthreads();
    for (int i = 0; i < 32; ++i) {
      int idx = i * 256 + t;
      o[(size_t)(idx >> 6) * 128 + h * 64 + (idx & 63)] = f2bf(buf[idx & 63][idx >> 6]);
    }
    __syncthreads();
  }
}

// ---------- precompute (Wd @ a_d) for all 8 (layer,conv) ----------
__global__ void precompute_wa(const float* __restrict__ W,
                              const float* __restrict__ att,
                              float* __restrict__ out) {
  int idx = blockIdx.x;   // 0..7
  int f = threadIdx.x;    // 0..127
  const float* w = W + (size_t)idx * 128 * 128 + (size_t)f * 128;
  const float* a = att + idx * 128;
  float s = 0.f;
  #pragma unroll 8
  for (int h = 0; h < 128; ++h) s += w[h] * a[h];
  out[idx * 128 + f] = s;
}

// ---------- MFMA dual GEMM: Hb1 = X@W1, Hb2 = X@W2 (bf16 out, f32 accum) ----
template <int XBF16>
__global__ __launch_bounds__(256) void gemm_dual(
    const void* __restrict__ Xv,
    const unsigned short* __restrict__ Wt1, const float* __restrict__ att1,
    unsigned short* __restrict__ Hb1, float* __restrict__ as1,
    const unsigned short* __restrict__ Wt2, const float* __restrict__ att2,
    unsigned short* __restrict__ Hb2, float* __restrict__ as2,
    const float* __restrict__ vdA, const float* __restrict__ vdB,
    float* __restrict__ adA, float* __restrict__ adB, int M) {
  __shared__ unsigned short Xt[64][136];    // [row][k], bf16, padded
  __shared__ unsigned short Wt[128][136];   // [n][k], bf16, padded
  const int t = threadIdx.x;
  const int row0 = blockIdx.x * 64;

  // stage X tile as bf16
  {
    int r = t >> 2;
    int cq = (t & 3) * 32;
    int gr = row0 + r;
    if (gr >= M) gr = M - 1;
    if (XBF16) {
      const unsigned short* Xb = (const unsigned short*)Xv;
      const uint4* src = (const uint4*)(Xb + (size_t)gr * 128 + cq);
      #pragma unroll
      for (int i = 0; i < 4; ++i) *(uint4*)&Xt[r][cq + i * 8] = src[i];
    } else {
      const float* Xf = (const float*)Xv;
      const float4* src = (const float4*)(Xf + (size_t)gr * 128 + cq);
      #pragma unroll
      for (int i = 0; i < 8; ++i) {
        float4 v = src[i];
        uint2 u;
        u.x = pack2(v.x, v.y);
        u.y = pack2(v.z, v.w);
        *(uint2*)&Xt[r][cq + i * 4] = u;
      }
    }
  }
  // stage W1
  {
    int n = t >> 1;
    int kh = (t & 1) * 64;
    const uint4* src = (const uint4*)(Wt1 + (size_t)n * 128 + kh);
    #pragma unroll
    for (int i = 0; i < 8; ++i) *(uint4*)&Wt[n][kh + i * 8] = src[i];
  }
  __syncthreads();

  // ad epilogue: rows 0..63 dot vdA (threads 0-63) / vdB (threads 64-127)
  if (t < 128) {
    int r = t & 63;
    const float* vd = (t < 64) ? vdA : vdB;
    float* adout = (t < 64) ? adA : adB;
    float sum = 0.f;
    #pragma unroll 4
    for (int k8 = 0; k8 < 16; ++k8) {
      uint4 u = *(const uint4*)&Xt[r][k8 * 8];
      const float* v = vd + k8 * 8;
      sum = fmaf(bflo(u.x), v[0], sum);
      sum = fmaf(bfhi(u.x), v[1], sum);
      sum = fmaf(bflo(u.y), v[2], sum);
      sum = fmaf(bfhi(u.y), v[3], sum);
      sum = fmaf(bflo(u.z), v[4], sum);
      sum = fmaf(bfhi(u.z), v[5], sum);
      sum = fmaf(bflo(u.w), v[6], sum);
      sum = fmaf(bfhi(u.w), v[7], sum);
    }
    int gr = row0 + r;
    if (gr < M) adout[gr] = sum;
  }

  const int lane = t & 63;
  const int wv = t >> 6;          // wave 0..3 -> rows ws..ws+15
  const int m = lane & 15;        // A-row / B-col / D-col
  const int g = lane >> 4;        // k-chunk group; D-rows g*4..g*4+3
  const int ws = wv * 16;

  for (int ww = 0; ww < 2; ++ww) {
    if (ww == 1) {
      __syncthreads();            // everyone done with W1
      int n = t >> 1;
      int kh = (t & 1) * 64;
      const uint4* src = (const uint4*)(Wt2 + (size_t)n * 128 + kh);
      #pragma unroll
      for (int i = 0; i < 8; ++i) *(uint4*)&Wt[n][kh + i * 8] = src[i];
      __syncthreads();
    }
    const float* att = ww ? att2 : att1;
    unsigned short* Hb = ww ? Hb2 : Hb1;
    float* as_ = ww ? as2 : as1;

    float4v acc[8];
    float4v z = {0.f, 0.f, 0.f, 0.f};
    #pragma unroll
    for (int nt = 0; nt < 8; ++nt) acc[nt] = z;

    #pragma unroll
    for (int ks = 0; ks < 4; ++ks) {
      short8v a = *(const short8v*)&Xt[ws + m][ks * 32 + g * 8];
      #pragma unroll
      for (int nt = 0; nt < 8; ++nt) {
        short8v b = *(const short8v*)&Wt[nt * 16 + m][ks * 32 + g * 8];
        acc[nt] = __builtin_amdgcn_mfma_f32_16x16x32_bf16(a, b, acc[nt], 0, 0, 0);
      }
    }

    // as epilogue: as[row] = sum_col acc[row][col]*att[col]
    {
      float attv[8];
      #pragma unroll
      for (int nt = 0; nt < 8; ++nt) attv[nt] = att[nt * 16 + m];
      #pragma unroll
      for (int r = 0; r < 4; ++r) {
        float s = 0.f;
        #pragma unroll
        for (int nt = 0; nt < 8; ++nt) s = fmaf(acc[nt][r], attv[nt], s);
        #pragma unroll
        for (int off = 1; off < 16; off <<= 1) s += __shfl_xor(s, off);
        if (m == 0) {
          int grow = row0 + ws + g * 4 + r;
          if (grow < M) as_[grow] = s;
        }
      }
    }

    // hs store: bf16, pack adjacent-col pairs via lane shuffle
    #pragma unroll
    for (int nt = 0; nt < 8; ++nt) {
      #pragma unroll
      for (int r = 0; r < 4; ++r) {
        float v = acc[nt][r];
        float vn = __shfl_xor(v, 1);
        if ((m & 1) == 0) {
          int grow = row0 + ws + g * 4 + r;
          if (grow < M) {
            *(unsigned*)(Hb + (size_t)grow * 128 + nt * 16 + m) = pack2(v, vn);
          }
        }
      }
    }
  }
}

// ---------- CSR build ----------
__global__ void hist4(const int* __restrict__ e0, const int* __restrict__ e1,
                      const int* __restrict__ e2, const int* __restrict__ e3,
                      int E, int* __restrict__ deg, int N) {
  int i = blockIdx.x * 256 + threadIdx.x;
  if (i >= E) return;
  int t = blockIdx.y;
  const int* ei = (t == 0) ? e0 : (t == 1) ? e1 : (t == 2) ? e2 : e3;
  atomicAdd(&deg[t * N + ei[E + i]], 1);
}

__global__ __launch_bounds__(1024) void scan4(const int* __restrict__ deg,
                                              int* __restrict__ rowptr, int N) {
  __shared__ int sums[1024];
  int t = threadIdx.x;
  int ty = blockIdx.x;
  const int* d = deg + (size_t)ty * N;
  int* rp = rowptr + (size_t)ty * (N + 1);
  int chunk = (N + 1023) / 1024;
  int lo = t * chunk;
  int hi = lo + chunk; if (hi > N) hi = N; if (lo > N) lo = N;
  int s = 0;
  for (int i = lo; i < hi; ++i) s += d[i];
  sums[t] = s;
  __syncthreads();
  for (int off = 1; off < 1024; off <<= 1) {
    int add = (t >= off) ? sums[t - off] : 0;
    __syncthreads();
    sums[t] += add;
    __syncthreads();
  }
  int run = (t == 0) ? 0 : sums[t - 1];
  for (int i = lo; i < hi; ++i) {
    rp[i] = run;
    run += d[i];
  }
  if (t == 1023) rp[N] = sums[1023];
}

__global__ void fill4(const int* __restrict__ e0, const int* __restrict__ e1,
                      const int* __restrict__ e2, const int* __restrict__ e3,
                      int E, const int* __restrict__ rowptr,
                      int* __restrict__ fill, int* __restrict__ csrc, int N) {
  int i = blockIdx.x * 256 + threadIdx.x;
  if (i >= E) return;
  int t = blockIdx.y;
  const int* ei = (t == 0) ? e0 : (t == 1) ? e1 : (t == 2) ? e2 : e3;
  int d = ei[E + i];
  int s = ei[i];
  int pos = rowptr[(size_t)t * (N + 1) + d] + atomicAdd(&fill[t * N + d], 1);
  csrc[(size_t)t * E + pos] = s;
}

// ---------- per-conv softmax agg: wave/node, no-max exp, 8-wide gathers ------
__device__ __forceinline__ float2 agg_conv(const int* __restrict__ rowptr,
                                           const int* __restrict__ csrc,
                                           const unsigned short* __restrict__ hs,
                                           const float* __restrict__ as_,
                                           float ad, int n, int lane) {
  int beg = rowptr[n], end = rowptr[n + 1];
  float lsum = 0.f;
  float2 acc = make_float2(0.f, 0.f);
  for (int c = beg; c < end; c += 64) {
    int k = c + lane;
    bool valid = k < end;
    int s = valid ? csrc[k] : 0;
    float e = valid ? (as_[s] + ad) : 0.f;
    e = e > 0.f ? e : NEG_SLOPE * e;
    float p = valid ? __expf(e) : 0.f;   // |e| small; softmax shift-invariant
    float ps = p;
    #pragma unroll
    for (int off = 32; off >= 1; off >>= 1) ps += __shfl_xor(ps, off);
    lsum += ps;
    int cnt = end - c; if (cnt > 64) cnt = 64;
    // 8-wide batches: 8 independent gathers in flight; slots >= cnt have p==0
    for (int base = 0; base < cnt; base += 8) {
      float pk0 = __shfl(p, base + 0), pk1 = __shfl(p, base + 1);
      float pk2 = __shfl(p, base + 2), pk3 = __shfl(p, base + 3);
      float pk4 = __shfl(p, base + 4), pk5 = __shfl(p, base + 5);
      float pk6 = __shfl(p, base + 6), pk7 = __shfl(p, base + 7);
      int sk0 = __shfl(s, base + 0), sk1 = __shfl(s, base + 1);
      int sk2 = __shfl(s, base + 2), sk3 = __shfl(s, base + 3);
      int sk4 = __shfl(s, base + 4), sk5 = __shfl(s, base + 5);
      int sk6 = __shfl(s, base + 6), sk7 = __shfl(s, base + 7);
      unsigned u0 = *(const unsigned*)(hs + (size_t)sk0 * 128 + lane * 2);
      unsigned u1 = *(const unsigned*)(hs + (size_t)sk1 * 128 + lane * 2);
      unsigned u2 = *(const unsigned*)(hs + (size_t)sk2 * 128 + lane * 2);
      unsigned u3 = *(const unsigned*)(hs + (size_t)sk3 * 128 + lane * 2);
      unsigned u4 = *(const unsigned*)(hs + (size_t)sk4 * 128 + lane * 2);
      unsigned u5 = *(const unsigned*)(hs + (size_t)sk5 * 128 + lane * 2);
      unsigned u6 = *(const unsigned*)(hs + (size_t)sk6 * 128 + lane * 2);
      unsigned u7 = *(const unsigned*)(hs + (size_t)sk7 * 128 + lane * 2);
      acc.x = fmaf(pk0, bflo(u0), acc.x); acc.y = fmaf(pk0, bfhi(u0), acc.y);
      acc.x = fmaf(pk1, bflo(u1), acc.x); acc.y = fmaf(pk1, bfhi(u1), acc.y);
      acc.x = fmaf(pk2, bflo(u2), acc.x); acc.y = fmaf(pk2, bfhi(u2), acc.y);
      acc.x = fmaf(pk3, bflo(u3), acc.x); acc.y = fmaf(pk3, bfhi(u3), acc.y);
      acc.x = fmaf(pk4, bflo(u4), acc.x); acc.y = fmaf(pk4, bfhi(u4), acc.y);
      acc.x = fmaf(pk5, bflo(u5), acc.x); acc.y = fmaf(pk5, bfhi(u5), acc.y);
      acc.x = fmaf(pk6, bflo(u6), acc.x); acc.y = fmaf(pk6, bfhi(u6), acc.y);
      acc.x = fmaf(pk7, bflo(u7), acc.x); acc.y = fmaf(pk7, bfhi(u7), acc.y);
    }
  }
  float inv = 1.f / fmaxf(lsum, 1e-16f);
  acc.x *= inv;
  acc.y *= inv;
  return acc;
}

// ---------- fused: out[n] = bf16(tanh(aggA + aggB + biasA + biasB)) ----------
__global__ __launch_bounds__(256) void fused_agg_store(
    const int* __restrict__ rA, const int* __restrict__ sA,
    const unsigned short* __restrict__ hA, const float* __restrict__ asA,
    const float* __restrict__ adA, const int* __restrict__ rB,
    const int* __restrict__ sB, const unsigned short* __restrict__ hB,
    const float* __restrict__ asB, const float* __restrict__ adB,
    const float* __restrict__ biasA, const float* __restrict__ biasB,
    unsigned short* __restrict__ out, int N) {
  int wave = (blockIdx.x * 256 + threadIdx.x) >> 6;
  int lane = threadIdx.x & 63;
  if (wave >= N) return;
  float2 a = agg_conv(rA, sA, hA, asA, adA[wave], wave, lane);
  float2 b = agg_conv(rB, sB, hB, asB, adB[wave], wave, lane);
  float2 b1 = *(const float2*)(biasA + lane * 2);
  float2 b2 = *(const float2*)(biasB + lane * 2);
  float vx = tanhf(a.x + b.x + b1.x + b2.x);
  float vy = tanhf(a.y + b.y + b1.y + b2.y);
  *(unsigned*)(out + (size_t)wave * 128 + lane * 2) = pack2(vx, vy);
}

// ---------- fused layer-2: tanh(...) pooled directly (atomic) ----------
__global__ __launch_bounds__(256) void fused_agg_pool(
    const int* __restrict__ rA, const int* __restrict__ sA,
    const unsigned short* __restrict__ hA, const float* __restrict__ asA,
    const float* __restrict__ adA, const int* __restrict__ rB,
    const int* __restrict__ sB, const unsigned short* __restrict__ hB,
    const float* __restrict__ asB, const float* __restrict__ adB,
    const float* __restrict__ biasA, const float* __restrict__ biasB,
    const int* __restrict__ batch, float* __restrict__ pool, int N) {
  int wave = (blockIdx.x * 256 + threadIdx.x) >> 6;
  int lane = threadIdx.x & 63;
  if (wave >= N) return;
  float2 a = agg_conv(rA, sA, hA, asA, adA[wave], wave, lane);
  float2 b = agg_conv(rB, sB, hB, asB, adB[wave], wave, lane);
  float2 b1 = *(const float2*)(biasA + lane * 2);
  float2 b2 = *(const float2*)(biasB + lane * 2);
  float vx = tanhf(a.x + b.x + b1.x + b2.x);
  float vy = tanhf(a.y + b.y + b1.y + b2.y);
  int bb = batch[wave];
  float* p = pool + (size_t)bb * 128 + lane * 2;
  unsafeAtomicAdd(p, vx);
  unsafeAtomicAdd(p + 1, vy);
}

// ---------- batch count histogram ----------
__global__ void batch_hist(const int* __restrict__ batch,
                           float* __restrict__ cnt, int N) {
  int i = blockIdx.x * 256 + threadIdx.x;
  if (i >= N) return;
  atomicAdd(&cnt[batch[i]], 1.0f);
}

// ---------- final ----------
__global__ void final_k(const float* __restrict__ pool_i,
                        const float* __restrict__ cnt_i,
                        const float* __restrict__ pool_j,
                        const float* __restrict__ cnt_j,
                        const float* __restrict__ lin_w,
                        const float* __restrict__ lin_b,
                        float* __restrict__ out) {
  int b = threadIdx.x;  // 256
  float ci = fmaxf(cnt_i[b], 1.f);
  float cj = fmaxf(cnt_j[b], 1.f);
  float acc = 0.f;
  #pragma unroll 4
  for (int f = 0; f < 128; ++f) {
    float x = 0.5f * (pool_i[(size_t)b * 128 + f] / ci +
                      pool_j[(size_t)b * 128 + f] / cj);
    acc += x * lin_w[f];
  }
  acc += lin_b[0];
  out[b] = 1.f / (1.f + __expf(-acc));
}

extern "C" void kernel_launch(void* const* d_in, const int* in_sizes, int n_in,
                              void* d_out, int out_size, void* d_ws,
                              size_t ws_size, hipStream_t stream) {
  const float* x_i = (const float*)d_in[0];
  const float* x_j = (const float*)d_in[1];
  const int* ei_arr[4] = {(const int*)d_in[2], (const int*)d_in[3],
                          (const int*)d_in[4], (const int*)d_in[5]};  // ii,jj,ij,ji
  const int* batch_i = (const int*)d_in[6];
  const int* batch_j = (const int*)d_in[7];
  const float* Ws = (const float*)d_in[8];
  const float* Wd = (const float*)d_in[9];
  const float* att_s = (const float*)d_in[10];
  const float* att_d = (const float*)d_in[11];
  const float* bias = (const float*)d_in[12];
  const float* lin_w = (const float*)d_in[13];
  const float* lin_b = (const float*)d_in[14];
  float* out = (float*)d_out;

  const int N = in_sizes[0] / 128;   // 100000
  const int E = in_sizes[2] / 2;     // 800000
  const size_t NF = (size_t)N * 128;

  char* w = (char*)d_ws;
  auto alloc = [&](size_t bytes) {
    char* p = w;
    w += (bytes + 255) & ~(size_t)255;
    return p;
  };
  unsigned short* bufA_i = (unsigned short*)alloc(NF * 2);
  unsigned short* bufA_j = (unsigned short*)alloc(NF * 2);
  unsigned short* hsb[4];
  for (int c = 0; c < 4; ++c) hsb[c] = (unsigned short*)alloc(NF * 2);
  int* csrc = (int*)alloc((size_t)4 * E * 4);
  int* rowptr = (int*)alloc((size_t)4 * (N + 1) * 4);
  int* deg = (int*)alloc((size_t)4 * N * 4);
  int* fillc = (int*)alloc((size_t)4 * N * 4);
  float* asb[4];
  for (int c = 0; c < 4; ++c) asb[c] = (float*)alloc((size_t)N * 4);
  float* adb[4];
  for (int c = 0; c < 4; ++c) adb[c] = (float*)alloc((size_t)N * 4);
  float* wdad = (float*)alloc(8 * 128 * 4);
  unsigned short* Wst = (unsigned short*)alloc(8 * 16384 * 2);
  float* pool = (float*)alloc(2 * 256 * 128 * 4);
  float* cnt = (float*)alloc(2 * 256 * 4);
  float* pool_i = pool;
  float* pool_j = pool + 256 * 128;
  float* cnt_i = cnt;
  float* cnt_j = cnt + 256;

  // ---- one-time prep ----
  w_to_bf16t<<<8, 256, 0, stream>>>(Ws, Wst);
  precompute_wa<<<8, 128, 0, stream>>>(Wd, att_d, wdad);

  // ---- CSR build (edge lists shared by both layers) ----
  hipMemsetAsync(deg, 0, (size_t)4 * N * 4, stream);
  hipMemsetAsync(fillc, 0, (size_t)4 * N * 4, stream);
  dim3 egrid((E + 255) / 256, 4);
  hist4<<<egrid, 256, 0, stream>>>(ei_arr[0], ei_arr[1], ei_arr[2], ei_arr[3],
                                   E, deg, N);
  scan4<<<4, 1024, 0, stream>>>(deg, rowptr, N);
  fill4<<<egrid, 256, 0, stream>>>(ei_arr[0], ei_arr[1], ei_arr[2], ei_arr[3],
                                   E, rowptr, fillc, csrc, N);

  hipMemsetAsync(pool, 0, 2 * 256 * 128 * 4, stream);
  hipMemsetAsync(cnt, 0, 2 * 256 * 4, stream);
  batch_hist<<<(N + 255) / 256, 256, 0, stream>>>(batch_i, cnt_i, N);
  batch_hist<<<(N + 255) / 256, 256, 0, stream>>>(batch_j, cnt_j, N);

  const int gemm_blocks = (N + 63) / 64;
  const int nodew_blocks = (N + 3) / 4;   // one wave per node

  // conv c0 = ii (src i, dst i); c1 = jj (src j, dst j);
  // conv c2 = ij (src i, dst j); c3 = ji (src j, dst i).
  // out_i <- aggregate convs {c0, c3}; out_j <- {c1, c2}.
  for (int l = 0; l < 2; ++l) {
    const void* cur_i = (l == 0) ? (const void*)x_i : (const void*)bufA_i;
    const void* cur_j = (l == 0) ? (const void*)x_j : (const void*)bufA_j;
    const size_t L = (size_t)l * 4;

    // x_i feeds hs/as for convs {0,2} (src=i) and ad for convs {0,3} (dst=i)
    // x_j feeds hs/as for convs {1,3} (src=j) and ad for convs {1,2} (dst=j)
    if (l == 0) {
      gemm_dual<0><<<gemm_blocks, 256, 0, stream>>>(
          cur_i, Wst + (L + 0) * 16384, att_s + (L + 0) * 128, hsb[0], asb[0],
          Wst + (L + 2) * 16384, att_s + (L + 2) * 128, hsb[2], asb[2],
          wdad + (L + 0) * 128, wdad + (L + 3) * 128, adb[0], adb[3], N);
      gemm_dual<0><<<gemm_blocks, 256, 0, stream>>>(
          cur_j, Wst + (L + 1) * 16384, att_s + (L + 1) * 128, hsb[1], asb[1],
          Wst + (L + 3) * 16384, att_s + (L + 3) * 128, hsb[3], asb[3],
          wdad + (L + 1) * 128, wdad + (L + 2) * 128, adb[1], adb[2], N);
    } else {
      gemm_dual<1><<<gemm_blocks, 256, 0, stream>>>(
          cur_i, Wst + (L + 0) * 16384, att_s + (L + 0) * 128, hsb[0], asb[0],
          Wst + (L + 2) * 16384, att_s + (L + 2) * 128, hsb[2], asb[2],
          wdad + (L + 0) * 128, wdad + (L + 3) * 128, adb[0], adb[3], N);
      gemm_dual<1><<<gemm_blocks, 256, 0, stream>>>(
          cur_j, Wst + (L + 1) * 16384, att_s + (L + 1) * 128, hsb[1], asb[1],
          Wst + (L + 3) * 16384, att_s + (L + 3) * 128, hsb[3], asb[3],
          wdad + (L + 1) * 128, wdad + (L + 2) * 128, adb[1], adb[2], N);
    }

    for (int pair = 0; pair < 2; ++pair) {
      int cA = (pair == 0) ? 0 : 1;
      int cB = (pair == 0) ? 3 : 2;
      const int* rA = rowptr + (size_t)cA * (N + 1);
      const int* rB = rowptr + (size_t)cB * (N + 1);
      const int* sA = csrc + (size_t)cA * E;
      const int* sB = csrc + (size_t)cB * E;
      const float* bA = bias + (L + cA) * 128;
      const float* bB = bias + (L + cB) * 128;
      if (l == 0) {
        unsigned short* outb = (pair == 0) ? bufA_i : bufA_j;
        fused_agg_store<<<nodew_blocks, 256, 0, stream>>>(
            rA, sA, hsb[cA], asb[cA], adb[cA], rB, sB, hsb[cB], asb[cB],
            adb[cB], bA, bB, outb, N);
      } else {
        const int* batch = (pair == 0) ? batch_i : batch_j;
        float* poolp = (pair == 0) ? pool_i : pool_j;
        fused_agg_pool<<<nodew_blocks, 256, 0, stream>>>(
            rA, sA, hsb[cA], asb[cA], adb[cA], rB, sB, hsb[cB], asb[cB],
            adb[cB], bA, bB, batch, poolp, N);
      }
    }
  }

  final_k<<<1, 256, 0, stream>>>(pool_i, cnt_i, pool_j, cnt_j, lin_w, lin_b,
                                 out);
}

// Round 8
// 1178.795 us; speedup vs baseline: 1.9404x; 1.3017x over previous
//
#include <hip/hip_runtime.h>

// HeteroGNN: 2 layers x 4 GATConv (single head), N=100000, E=800000, C=128.
// R8: batch_hist deleted (sorted batch -> binary-search counts inside final_k;
// it was 400us of same-address float CAS atomics). agg broadcast switched from
// __shfl (ds_bpermute, lgkm latency) to v_readlane (wave-uniform index).

#define NEG_SLOPE 0.2f

typedef __attribute__((ext_vector_type(8))) short short8v;
typedef __attribute__((ext_vector_type(4))) float float4v;

__device__ __forceinline__ unsigned short f2bf(float f) {
  unsigned u = __float_as_uint(f);
  unsigned r = (u + 0x7FFFu + ((u >> 16) & 1u)) >> 16;
  return (unsigned short)r;
}
__device__ __forceinline__ unsigned pack2(float a, float b) {
  return (unsigned)f2bf(a) | ((unsigned)f2bf(b) << 16);
}
__device__ __forceinline__ float bflo(unsigned u) {
  return __uint_as_float(u << 16);
}
__device__ __forceinline__ float bfhi(unsigned u) {
  return __uint_as_float(u & 0xFFFF0000u);
}
__device__ __forceinline__ float rl_f(float x, int lane) {
  return __int_as_float(__builtin_amdgcn_readlane(__float_as_int(x), lane));
}
__device__ __forceinline__ int rl_i(int x, int lane) {
  return __builtin_amdgcn_readlane(x, lane);
}

// ---------- W -> bf16 transposed (Wt[n][k] = W[k][n]), 8 matrices ----------
__global__ __launch_bounds__(256) void w_to_bf16t(const float* __restrict__ W,
                                                  unsigned short* __restrict__ Wt) {
  __shared__ float buf[64][129];
  int b = blockIdx.x, t = threadIdx.x;
  const float* w = W + (size_t)b * 16384;
  unsigned short* o = Wt + (size_t)b * 16384;
  for (int h = 0; h < 2; ++h) {
    for (int i = 0; i < 32; ++i) {
      int idx = i * 256 + t;
      buf[idx >> 7][idx & 127] = w[(size_t)(h * 64 + (idx >> 7)) * 128 + (idx & 127)];
    }
    __syncthreads();
    for (int i = 0; i < 32; ++i) {
      int idx = i * 256 + t;
      o[(size_t)(idx >> 6) * 128 + h * 64 + (idx & 63)] = f2bf(buf[idx & 63][idx >> 6]);
    }
    __syncthreads();
  }
}

// ---------- precompute (Wd @ a_d) for all 8 (layer,conv) ----------
__global__ void precompute_wa(const float* __restrict__ W,
                              const float* __restrict__ att,
                              float* __restrict__ out) {
  int idx = blockIdx.x;   // 0..7
  int f = threadIdx.x;    // 0..127
  const float* w = W + (size_t)idx * 128 * 128 + (size_t)f * 128;
  const float* a = att + idx * 128;
  float s = 0.f;
  #pragma unroll 8
  for (int h = 0; h < 128; ++h) s += w[h] * a[h];
  out[idx * 128 + f] = s;
}

// ---------- MFMA dual GEMM: Hb1 = X@W1, Hb2 = X@W2 (bf16 out, f32 accum) ----
template <int XBF16>
__global__ __launch_bounds__(256) void gemm_dual(
    const void* __restrict__ Xv,
    const unsigned short* __restrict__ Wt1, const float* __restrict__ att1,
    unsigned short* __restrict__ Hb1, float* __restrict__ as1,
    const unsigned short* __restrict__ Wt2, const float* __restrict__ att2,
    unsigned short* __restrict__ Hb2, float* __restrict__ as2,
    const float* __restrict__ vdA, const float* __restrict__ vdB,
    float* __restrict__ adA, float* __restrict__ adB, int M) {
  __shared__ unsigned short Xt[64][136];    // [row][k], bf16, padded
  __shared__ unsigned short Wt[128][136];   // [n][k], bf16, padded
  const int t = threadIdx.x;
  const int row0 = blockIdx.x * 64;

  // stage X tile as bf16
  {
    int r = t >> 2;
    int cq = (t & 3) * 32;
    int gr = row0 + r;
    if (gr >= M) gr = M - 1;
    if (XBF16) {
      const unsigned short* Xb = (const unsigned short*)Xv;
      const uint4* src = (const uint4*)(Xb + (size_t)gr * 128 + cq);
      #pragma unroll
      for (int i = 0; i < 4; ++i) *(uint4*)&Xt[r][cq + i * 8] = src[i];
    } else {
      const float* Xf = (const float*)Xv;
      const float4* src = (const float4*)(Xf + (size_t)gr * 128 + cq);
      #pragma unroll
      for (int i = 0; i < 8; ++i) {
        float4 v = src[i];
        uint2 u;
        u.x = pack2(v.x, v.y);
        u.y = pack2(v.z, v.w);
        *(uint2*)&Xt[r][cq + i * 4] = u;
      }
    }
  }
  // stage W1
  {
    int n = t >> 1;
    int kh = (t & 1) * 64;
    const uint4* src = (const uint4*)(Wt1 + (size_t)n * 128 + kh);
    #pragma unroll
    for (int i = 0; i < 8; ++i) *(uint4*)&Wt[n][kh + i * 8] = src[i];
  }
  __syncthreads();

  // ad epilogue: rows 0..63 dot vdA (threads 0-63) / vdB (threads 64-127)
  if (t < 128) {
    int r = t & 63;
    const float* vd = (t < 64) ? vdA : vdB;
    float* adout = (t < 64) ? adA : adB;
    float sum = 0.f;
    #pragma unroll 4
    for (int k8 = 0; k8 < 16; ++k8) {
      uint4 u = *(const uint4*)&Xt[r][k8 * 8];
      const float* v = vd + k8 * 8;
      sum = fmaf(bflo(u.x), v[0], sum);
      sum = fmaf(bfhi(u.x), v[1], sum);
      sum = fmaf(bflo(u.y), v[2], sum);
      sum = fmaf(bfhi(u.y), v[3], sum);
      sum = fmaf(bflo(u.z), v[4], sum);
      sum = fmaf(bfhi(u.z), v[5], sum);
      sum = fmaf(bflo(u.w), v[6], sum);
      sum = fmaf(bfhi(u.w), v[7], sum);
    }
    int gr = row0 + r;
    if (gr < M) adout[gr] = sum;
  }

  const int lane = t & 63;
  const int wv = t >> 6;          // wave 0..3 -> rows ws..ws+15
  const int m = lane & 15;        // A-row / B-col / D-col
  const int g = lane >> 4;        // k-chunk group; D-rows g*4..g*4+3
  const int ws = wv * 16;

  for (int ww = 0; ww < 2; ++ww) {
    if (ww == 1) {
      __syncthreads();            // everyone done with W1
      int n = t >> 1;
      int kh = (t & 1) * 64;
      const uint4* src = (const uint4*)(Wt2 + (size_t)n * 128 + kh);
      #pragma unroll
      for (int i = 0; i < 8; ++i) *(uint4*)&Wt[n][kh + i * 8] = src[i];
      __syncthreads();
    }
    const float* att = ww ? att2 : att1;
    unsigned short* Hb = ww ? Hb2 : Hb1;
    float* as_ = ww ? as2 : as1;

    float4v acc[8];
    float4v z = {0.f, 0.f, 0.f, 0.f};
    #pragma unroll
    for (int nt = 0; nt < 8; ++nt) acc[nt] = z;

    #pragma unroll
    for (int ks = 0; ks < 4; ++ks) {
      short8v a = *(const short8v*)&Xt[ws + m][ks * 32 + g * 8];
      #pragma unroll
      for (int nt = 0; nt < 8; ++nt) {
        short8v b = *(const short8v*)&Wt[nt * 16 + m][ks * 32 + g * 8];
        acc[nt] = __builtin_amdgcn_mfma_f32_16x16x32_bf16(a, b, acc[nt], 0, 0, 0);
      }
    }

    // as epilogue: as[row] = sum_col acc[row][col]*att[col]
    {
      float attv[8];
      #pragma unroll
      for (int nt = 0; nt < 8; ++nt) attv[nt] = att[nt * 16 + m];
      #pragma unroll
      for (int r = 0; r < 4; ++r) {
        float s = 0.f;
        #pragma unroll
        for (int nt = 0; nt < 8; ++nt) s = fmaf(acc[nt][r], attv[nt], s);
        #pragma unroll
        for (int off = 1; off < 16; off <<= 1) s += __shfl_xor(s, off);
        if (m == 0) {
          int grow = row0 + ws + g * 4 + r;
          if (grow < M) as_[grow] = s;
        }
      }
    }

    // hs store: bf16, pack adjacent-col pairs via lane shuffle
    #pragma unroll
    for (int nt = 0; nt < 8; ++nt) {
      #pragma unroll
      for (int r = 0; r < 4; ++r) {
        float v = acc[nt][r];
        float vn = __shfl_xor(v, 1);
        if ((m & 1) == 0) {
          int grow = row0 + ws + g * 4 + r;
          if (grow < M) {
            *(unsigned*)(Hb + (size_t)grow * 128 + nt * 16 + m) = pack2(v, vn);
          }
        }
      }
    }
  }
}

// ---------- CSR build ----------
__global__ void hist4(const int* __restrict__ e0, const int* __restrict__ e1,
                      const int* __restrict__ e2, const int* __restrict__ e3,
                      int E, int* __restrict__ deg, int N) {
  int i = blockIdx.x * 256 + threadIdx.x;
  if (i >= E) return;
  int t = blockIdx.y;
  const int* ei = (t == 0) ? e0 : (t == 1) ? e1 : (t == 2) ? e2 : e3;
  atomicAdd(&deg[t * N + ei[E + i]], 1);
}

__global__ __launch_bounds__(1024) void scan4(const int* __restrict__ deg,
                                              int* __restrict__ rowptr, int N) {
  __shared__ int sums[1024];
  int t = threadIdx.x;
  int ty = blockIdx.x;
  const int* d = deg + (size_t)ty * N;
  int* rp = rowptr + (size_t)ty * (N + 1);
  int chunk = (N + 1023) / 1024;
  int lo = t * chunk;
  int hi = lo + chunk; if (hi > N) hi = N; if (lo > N) lo = N;
  int s = 0;
  for (int i = lo; i < hi; ++i) s += d[i];
  sums[t] = s;
  __syncthreads();
  for (int off = 1; off < 1024; off <<= 1) {
    int add = (t >= off) ? sums[t - off] : 0;
    __syncthreads();
    sums[t] += add;
    __syncthreads();
  }
  int run = (t == 0) ? 0 : sums[t - 1];
  for (int i = lo; i < hi; ++i) {
    rp[i] = run;
    run += d[i];
  }
  if (t == 1023) rp[N] = sums[1023];
}

__global__ void fill4(const int* __restrict__ e0, const int* __restrict__ e1,
                      const int* __restrict__ e2, const int* __restrict__ e3,
                      int E, const int* __restrict__ rowptr,
                      int* __restrict__ fill, int* __restrict__ csrc, int N) {
  int i = blockIdx.x * 256 + threadIdx.x;
  if (i >= E) return;
  int t = blockIdx.y;
  const int* ei = (t == 0) ? e0 : (t == 1) ? e1 : (t == 2) ? e2 : e3;
  int d = ei[E + i];
  int s = ei[i];
  int pos = rowptr[(size_t)t * (N + 1) + d] + atomicAdd(&fill[t * N + d], 1);
  csrc[(size_t)t * E + pos] = s;
}

// ---------- per-conv softmax agg: wave/node, readlane broadcast, 8-wide ------
__device__ __forceinline__ float2 agg_conv(const int* __restrict__ rowptr,
                                           const int* __restrict__ csrc,
                                           const unsigned short* __restrict__ hs,
                                           const float* __restrict__ as_,
                                           float ad, int n, int lane) {
  int beg = rowptr[n], end = rowptr[n + 1];
  float lsum = 0.f;
  float2 acc = make_float2(0.f, 0.f);
  for (int c = beg; c < end; c += 64) {
    int k = c + lane;
    bool valid = k < end;
    int s = valid ? csrc[k] : 0;
    float e = valid ? (as_[s] + ad) : 0.f;
    e = e > 0.f ? e : NEG_SLOPE * e;
    float p = valid ? __expf(e) : 0.f;   // |e| small; softmax shift-invariant
    float ps = p;
    #pragma unroll
    for (int off = 32; off >= 1; off >>= 1) ps += __shfl_xor(ps, off);
    lsum += ps;
    int cnt = end - c; if (cnt > 64) cnt = 64;
    // 8-wide batches; broadcast via v_readlane (index is wave-uniform)
    for (int base = 0; base < cnt; base += 8) {
      float pk0 = rl_f(p, base + 0), pk1 = rl_f(p, base + 1);
      float pk2 = rl_f(p, base + 2), pk3 = rl_f(p, base + 3);
      float pk4 = rl_f(p, base + 4), pk5 = rl_f(p, base + 5);
      float pk6 = rl_f(p, base + 6), pk7 = rl_f(p, base + 7);
      int sk0 = rl_i(s, base + 0), sk1 = rl_i(s, base + 1);
      int sk2 = rl_i(s, base + 2), sk3 = rl_i(s, base + 3);
      int sk4 = rl_i(s, base + 4), sk5 = rl_i(s, base + 5);
      int sk6 = rl_i(s, base + 6), sk7 = rl_i(s, base + 7);
      unsigned u0 = *(const unsigned*)(hs + (size_t)sk0 * 128 + lane * 2);
      unsigned u1 = *(const unsigned*)(hs + (size_t)sk1 * 128 + lane * 2);
      unsigned u2 = *(const unsigned*)(hs + (size_t)sk2 * 128 + lane * 2);
      unsigned u3 = *(const unsigned*)(hs + (size_t)sk3 * 128 + lane * 2);
      unsigned u4 = *(const unsigned*)(hs + (size_t)sk4 * 128 + lane * 2);
      unsigned u5 = *(const unsigned*)(hs + (size_t)sk5 * 128 + lane * 2);
      unsigned u6 = *(const unsigned*)(hs + (size_t)sk6 * 128 + lane * 2);
      unsigned u7 = *(const unsigned*)(hs + (size_t)sk7 * 128 + lane * 2);
      acc.x = fmaf(pk0, bflo(u0), acc.x); acc.y = fmaf(pk0, bfhi(u0), acc.y);
      acc.x = fmaf(pk1, bflo(u1), acc.x); acc.y = fmaf(pk1, bfhi(u1), acc.y);
      acc.x = fmaf(pk2, bflo(u2), acc.x); acc.y = fmaf(pk2, bfhi(u2), acc.y);
      acc.x = fmaf(pk3, bflo(u3), acc.x); acc.y = fmaf(pk3, bfhi(u3), acc.y);
      acc.x = fmaf(pk4, bflo(u4), acc.x); acc.y = fmaf(pk4, bfhi(u4), acc.y);
      acc.x = fmaf(pk5, bflo(u5), acc.x); acc.y = fmaf(pk5, bfhi(u5), acc.y);
      acc.x = fmaf(pk6, bflo(u6), acc.x); acc.y = fmaf(pk6, bfhi(u6), acc.y);
      acc.x = fmaf(pk7, bflo(u7), acc.x); acc.y = fmaf(pk7, bfhi(u7), acc.y);
    }
  }
  float inv = 1.f / fmaxf(lsum, 1e-16f);
  acc.x *= inv;
  acc.y *= inv;
  return acc;
}

// ---------- fused: out[n] = bf16(tanh(aggA + aggB + biasA + biasB)) ----------
__global__ __launch_bounds__(256) void fused_agg_store(
    const int* __restrict__ rA, const int* __restrict__ sA,
    const unsigned short* __restrict__ hA, const float* __restrict__ asA,
    const float* __restrict__ adA, const int* __restrict__ rB,
    const int* __restrict__ sB, const unsigned short* __restrict__ hB,
    const float* __restrict__ asB, const float* __restrict__ adB,
    const float* __restrict__ biasA, const float* __restrict__ biasB,
    unsigned short* __restrict__ out, int N) {
  int wave = (blockIdx.x * 256 + threadIdx.x) >> 6;
  int lane = threadIdx.x & 63;
  if (wave >= N) return;
  float2 a = agg_conv(rA, sA, hA, asA, adA[wave], wave, lane);
  float2 b = agg_conv(rB, sB, hB, asB, adB[wave], wave, lane);
  float2 b1 = *(const float2*)(biasA + lane * 2);
  float2 b2 = *(const float2*)(biasB + lane * 2);
  float vx = tanhf(a.x + b.x + b1.x + b2.x);
  float vy = tanhf(a.y + b.y + b1.y + b2.y);
  *(unsigned*)(out + (size_t)wave * 128 + lane * 2) = pack2(vx, vy);
}

// ---------- fused layer-2: tanh(...) pooled directly (atomic) ----------
__global__ __launch_bounds__(256) void fused_agg_pool(
    const int* __restrict__ rA, const int* __restrict__ sA,
    const unsigned short* __restrict__ hA, const float* __restrict__ asA,
    const float* __restrict__ adA, const int* __restrict__ rB,
    const int* __restrict__ sB, const unsigned short* __restrict__ hB,
    const float* __restrict__ asB, const float* __restrict__ adB,
    const float* __restrict__ biasA, const float* __restrict__ biasB,
    const int* __restrict__ batch, float* __restrict__ pool, int N) {
  int wave = (blockIdx.x * 256 + threadIdx.x) >> 6;
  int lane = threadIdx.x & 63;
  if (wave >= N) return;
  float2 a = agg_conv(rA, sA, hA, asA, adA[wave], wave, lane);
  float2 b = agg_conv(rB, sB, hB, asB, adB[wave], wave, lane);
  float2 b1 = *(const float2*)(biasA + lane * 2);
  float2 b2 = *(const float2*)(biasB + lane * 2);
  float vx = tanhf(a.x + b.x + b1.x + b2.x);
  float vy = tanhf(a.y + b.y + b1.y + b2.y);
  int bb = batch[wave];
  float* p = pool + (size_t)bb * 128 + lane * 2;
  unsafeAtomicAdd(p, vx);
  unsafeAtomicAdd(p + 1, vy);
}

// ---------- final: counts via binary search over the SORTED batch arrays ----
__device__ __forceinline__ int lower_bound_i(const int* __restrict__ a, int n,
                                             int v) {
  int lo = 0, hi = n;
  while (lo < hi) {
    int mid = (lo + hi) >> 1;
    if (a[mid] < v) lo = mid + 1; else hi = mid;
  }
  return lo;
}

__global__ void final_k(const float* __restrict__ pool_i,
                        const int* __restrict__ batch_i,
                        const float* __restrict__ pool_j,
                        const int* __restrict__ batch_j, int N,
                        const float* __restrict__ lin_w,
                        const float* __restrict__ lin_b,
                        float* __restrict__ out) {
  int b = threadIdx.x;  // 256
  float ci = (float)(lower_bound_i(batch_i, N, b + 1) -
                     lower_bound_i(batch_i, N, b));
  float cj = (float)(lower_bound_i(batch_j, N, b + 1) -
                     lower_bound_i(batch_j, N, b));
  ci = fmaxf(ci, 1.f);
  cj = fmaxf(cj, 1.f);
  float acc = 0.f;
  #pragma unroll 4
  for (int f = 0; f < 128; ++f) {
    float x = 0.5f * (pool_i[(size_t)b * 128 + f] / ci +
                      pool_j[(size_t)b * 128 + f] / cj);
    acc += x * lin_w[f];
  }
  acc += lin_b[0];
  out[b] = 1.f / (1.f + __expf(-acc));
}

extern "C" void kernel_launch(void* const* d_in, const int* in_sizes, int n_in,
                              void* d_out, int out_size, void* d_ws,
                              size_t ws_size, hipStream_t stream) {
  const float* x_i = (const float*)d_in[0];
  const float* x_j = (const float*)d_in[1];
  const int* ei_arr[4] = {(const int*)d_in[2], (const int*)d_in[3],
                          (const int*)d_in[4], (const int*)d_in[5]};  // ii,jj,ij,ji
  const int* batch_i = (const int*)d_in[6];
  const int* batch_j = (const int*)d_in[7];
  const float* Ws = (const float*)d_in[8];
  const float* Wd = (const float*)d_in[9];
  const float* att_s = (const float*)d_in[10];
  const float* att_d = (const float*)d_in[11];
  const float* bias = (const float*)d_in[12];
  const float* lin_w = (const float*)d_in[13];
  const float* lin_b = (const float*)d_in[14];
  float* out = (float*)d_out;

  const int N = in_sizes[0] / 128;   // 100000
  const int E = in_sizes[2] / 2;     // 800000
  const size_t NF = (size_t)N * 128;

  char* w = (char*)d_ws;
  auto alloc = [&](size_t bytes) {
    char* p = w;
    w += (bytes + 255) & ~(size_t)255;
    return p;
  };
  unsigned short* bufA_i = (unsigned short*)alloc(NF * 2);
  unsigned short* bufA_j = (unsigned short*)alloc(NF * 2);
  unsigned short* hsb[4];
  for (int c = 0; c < 4; ++c) hsb[c] = (unsigned short*)alloc(NF * 2);
  int* csrc = (int*)alloc((size_t)4 * E * 4);
  int* rowptr = (int*)alloc((size_t)4 * (N + 1) * 4);
  int* deg = (int*)alloc((size_t)4 * N * 4);
  int* fillc = (int*)alloc((size_t)4 * N * 4);
  float* asb[4];
  for (int c = 0; c < 4; ++c) asb[c] = (float*)alloc((size_t)N * 4);
  float* adb[4];
  for (int c = 0; c < 4; ++c) adb[c] = (float*)alloc((size_t)N * 4);
  float* wdad = (float*)alloc(8 * 128 * 4);
  unsigned short* Wst = (unsigned short*)alloc(8 * 16384 * 2);
  float* pool = (float*)alloc(2 * 256 * 128 * 4);
  float* pool_i = pool;
  float* pool_j = pool + 256 * 128;

  // ---- one-time prep ----
  w_to_bf16t<<<8, 256, 0, stream>>>(Ws, Wst);
  precompute_wa<<<8, 128, 0, stream>>>(Wd, att_d, wdad);

  // ---- CSR build (edge lists shared by both layers) ----
  hipMemsetAsync(deg, 0, (size_t)4 * N * 4, stream);
  hipMemsetAsync(fillc, 0, (size_t)4 * N * 4, stream);
  dim3 egrid((E + 255) / 256, 4);
  hist4<<<egrid, 256, 0, stream>>>(ei_arr[0], ei_arr[1], ei_arr[2], ei_arr[3],
                                   E, deg, N);
  scan4<<<4, 1024, 0, stream>>>(deg, rowptr, N);
  fill4<<<egrid, 256, 0, stream>>>(ei_arr[0], ei_arr[1], ei_arr[2], ei_arr[3],
                                   E, rowptr, fillc, csrc, N);

  hipMemsetAsync(pool, 0, 2 * 256 * 128 * 4, stream);

  const int gemm_blocks = (N + 63) / 64;
  const int nodew_blocks = (N + 3) / 4;   // one wave per node

  // conv c0 = ii (src i, dst i); c1 = jj (src j, dst j);
  // conv c2 = ij (src i, dst j); c3 = ji (src j, dst i).
  // out_i <- aggregate convs {c0, c3}; out_j <- {c1, c2}.
  for (int l = 0; l < 2; ++l) {
    const void* cur_i = (l == 0) ? (const void*)x_i : (const void*)bufA_i;
    const void* cur_j = (l == 0) ? (const void*)x_j : (const void*)bufA_j;
    const size_t L = (size_t)l * 4;

    if (l == 0) {
      gemm_dual<0><<<gemm_blocks, 256, 0, stream>>>(
          cur_i, Wst + (L + 0) * 16384, att_s + (L + 0) * 128, hsb[0], asb[0],
          Wst + (L + 2) * 16384, att_s + (L + 2) * 128, hsb[2], asb[2],
          wdad + (L + 0) * 128, wdad + (L + 3) * 128, adb[0], adb[3], N);
      gemm_dual<0><<<gemm_blocks, 256, 0, stream>>>(
          cur_j, Wst + (L + 1) * 16384, att_s + (L + 1) * 128, hsb[1], asb[1],
          Wst + (L + 3) * 16384, att_s + (L + 3) * 128, hsb[3], asb[3],
          wdad + (L + 1) * 128, wdad + (L + 2) * 128, adb[1], adb[2], N);
    } else {
      gemm_dual<1><<<gemm_blocks, 256, 0, stream>>>(
          cur_i, Wst + (L + 0) * 16384, att_s + (L + 0) * 128, hsb[0], asb[0],
          Wst + (L + 2) * 16384, att_s + (L + 2) * 128, hsb[2], asb[2],
          wdad + (L + 0) * 128, wdad + (L + 3) * 128, adb[0], adb[3], N);
      gemm_dual<1><<<gemm_blocks, 256, 0, stream>>>(
          cur_j, Wst + (L + 1) * 16384, att_s + (L + 1) * 128, hsb[1], asb[1],
          Wst + (L + 3) * 16384, att_s + (L + 3) * 128, hsb[3], asb[3],
          wdad + (L + 1) * 128, wdad + (L + 2) * 128, adb[1], adb[2], N);
    }

    for (int pair = 0; pair < 2; ++pair) {
      int cA = (pair == 0) ? 0 : 1;
      int cB = (pair == 0) ? 3 : 2;
      const int* rA = rowptr + (size_t)cA * (N + 1);
      const int* rB = rowptr + (size_t)cB * (N + 1);
      const int* sA = csrc + (size_t)cA * E;
      const int* sB = csrc + (size_t)cB * E;
      const float* bA = bias + (L + cA) * 128;
      const float* bB = bias + (L + cB) * 128;
      if (l == 0) {
        unsigned short* outb = (pair == 0) ? bufA_i : bufA_j;
        fused_agg_store<<<nodew_blocks, 256, 0, stream>>>(
            rA, sA, hsb[cA], asb[cA], adb[cA], rB, sB, hsb[cB], asb[cB],
            adb[cB], bA, bB, outb, N);
      } else {
        const int* batch = (pair == 0) ? batch_i : batch_j;
        float* poolp = (pair == 0) ? pool_i : pool_j;
        fused_agg_pool<<<nodew_blocks, 256, 0, stream>>>(
            rA, sA, hsb[cA], asb[cA], adb[cA], rB, sB, hsb[cB], asb[cB],
            adb[cB], bA, bB, batch, poolp, N);
      }
    }
  }

  final_k<<<1, 256, 0, stream>>>(pool_i, batch_i, pool_j, batch_j, N, lin_w,
                                 lin_b, out);
}

// Round 9
// 1108.968 us; speedup vs baseline: 2.0626x; 1.0630x over previous
//
#include <hip/hip_runtime.h>

// HeteroGNN: 2 layers x 4 GATConv (single head), N=100000, E=800000, C=128.
// R9: agg_pair interleaves both convs of a node in one loop (2x independent
// gather chains), lsum computed from broadcast p's on all lanes (shfl_xor
// reduction deleted), and the two conv-pairs of a layer merged into one
// dispatch via blockIdx.y. Rest as R8 (MFMA gemm_dual, bf16 hs, binary-search
// counts in final_k).

#define NEG_SLOPE 0.2f

typedef __attribute__((ext_vector_type(8))) short short8v;
typedef __attribute__((ext_vector_type(4))) float float4v;

__device__ __forceinline__ unsigned short f2bf(float f) {
  unsigned u = __float_as_uint(f);
  unsigned r = (u + 0x7FFFu + ((u >> 16) & 1u)) >> 16;
  return (unsigned short)r;
}
__device__ __forceinline__ unsigned pack2(float a, float b) {
  return (unsigned)f2bf(a) | ((unsigned)f2bf(b) << 16);
}
__device__ __forceinline__ float bflo(unsigned u) {
  return __uint_as_float(u << 16);
}
__device__ __forceinline__ float bfhi(unsigned u) {
  return __uint_as_float(u & 0xFFFF0000u);
}
__device__ __forceinline__ float rl_f(float x, int lane) {
  return __int_as_float(__builtin_amdgcn_readlane(__float_as_int(x), lane));
}
__device__ __forceinline__ int rl_i(int x, int lane) {
  return __builtin_amdgcn_readlane(x, lane);
}

// ---------- W -> bf16 transposed (Wt[n][k] = W[k][n]), 8 matrices ----------
__global__ __launch_bounds__(256) void w_to_bf16t(const float* __restrict__ W,
                                                  unsigned short* __restrict__ Wt) {
  __shared__ float buf[64][129];
  int b = blockIdx.x, t = threadIdx.x;
  const float* w = W + (size_t)b * 16384;
  unsigned short* o = Wt + (size_t)b * 16384;
  for (int h = 0; h < 2; ++h) {
    for (int i = 0; i < 32; ++i) {
      int idx = i * 256 + t;
      buf[idx >> 7][idx & 127] = w[(size_t)(h * 64 + (idx >> 7)) * 128 + (idx & 127)];
    }
    __syncthreads();
    for (int i = 0; i < 32; ++i) {
      int idx = i * 256 + t;
      o[(size_t)(idx >> 6) * 128 + h * 64 + (idx & 63)] = f2bf(buf[idx & 63][idx >> 6]);
    }
    __syncthreads();
  }
}

// ---------- precompute (Wd @ a_d) for all 8 (layer,conv) ----------
__global__ void precompute_wa(const float* __restrict__ W,
                              const float* __restrict__ att,
                              float* __restrict__ out) {
  int idx = blockIdx.x;   // 0..7
  int f = threadIdx.x;    // 0..127
  const float* w = W + (size_t)idx * 128 * 128 + (size_t)f * 128;
  const float* a = att + idx * 128;
  float s = 0.f;
  #pragma unroll 8
  for (int h = 0; h < 128; ++h) s += w[h] * a[h];
  out[idx * 128 + f] = s;
}

// ---------- MFMA dual GEMM: Hb1 = X@W1, Hb2 = X@W2 (bf16 out, f32 accum) ----
template <int XBF16>
__global__ __launch_bounds__(256) void gemm_dual(
    const void* __restrict__ Xv,
    const unsigned short* __restrict__ Wt1, const float* __restrict__ att1,
    unsigned short* __restrict__ Hb1, float* __restrict__ as1,
    const unsigned short* __restrict__ Wt2, const float* __restrict__ att2,
    unsigned short* __restrict__ Hb2, float* __restrict__ as2,
    const float* __restrict__ vdA, const float* __restrict__ vdB,
    float* __restrict__ adA, float* __restrict__ adB, int M) {
  __shared__ unsigned short Xt[64][136];    // [row][k], bf16, padded
  __shared__ unsigned short Wt[128][136];   // [n][k], bf16, padded
  const int t = threadIdx.x;
  const int row0 = blockIdx.x * 64;

  // stage X tile as bf16
  {
    int r = t >> 2;
    int cq = (t & 3) * 32;
    int gr = row0 + r;
    if (gr >= M) gr = M - 1;
    if (XBF16) {
      const unsigned short* Xb = (const unsigned short*)Xv;
      const uint4* src = (const uint4*)(Xb + (size_t)gr * 128 + cq);
      #pragma unroll
      for (int i = 0; i < 4; ++i) *(uint4*)&Xt[r][cq + i * 8] = src[i];
    } else {
      const float* Xf = (const float*)Xv;
      const float4* src = (const float4*)(Xf + (size_t)gr * 128 + cq);
      #pragma unroll
      for (int i = 0; i < 8; ++i) {
        float4 v = src[i];
        uint2 u;
        u.x = pack2(v.x, v.y);
        u.y = pack2(v.z, v.w);
        *(uint2*)&Xt[r][cq + i * 4] = u;
      }
    }
  }
  // stage W1
  {
    int n = t >> 1;
    int kh = (t & 1) * 64;
    const uint4* src = (const uint4*)(Wt1 + (size_t)n * 128 + kh);
    #pragma unroll
    for (int i = 0; i < 8; ++i) *(uint4*)&Wt[n][kh + i * 8] = src[i];
  }
  __syncthreads();

  // ad epilogue: rows 0..63 dot vdA (threads 0-63) / vdB (threads 64-127)
  if (t < 128) {
    int r = t & 63;
    const float* vd = (t < 64) ? vdA : vdB;
    float* adout = (t < 64) ? adA : adB;
    float sum = 0.f;
    #pragma unroll 4
    for (int k8 = 0; k8 < 16; ++k8) {
      uint4 u = *(const uint4*)&Xt[r][k8 * 8];
      const float* v = vd + k8 * 8;
      sum = fmaf(bflo(u.x), v[0], sum);
      sum = fmaf(bfhi(u.x), v[1], sum);
      sum = fmaf(bflo(u.y), v[2], sum);
      sum = fmaf(bfhi(u.y), v[3], sum);
      sum = fmaf(bflo(u.z), v[4], sum);
      sum = fmaf(bfhi(u.z), v[5], sum);
      sum = fmaf(bflo(u.w), v[6], sum);
      sum = fmaf(bfhi(u.w), v[7], sum);
    }
    int gr = row0 + r;
    if (gr < M) adout[gr] = sum;
  }

  const int lane = t & 63;
  const int wv = t >> 6;          // wave 0..3 -> rows ws..ws+15
  const int m = lane & 15;        // A-row / B-col / D-col
  const int g = lane >> 4;        // k-chunk group; D-rows g*4..g*4+3
  const int ws = wv * 16;

  for (int ww = 0; ww < 2; ++ww) {
    if (ww == 1) {
      __syncthreads();            // everyone done with W1
      int n = t >> 1;
      int kh = (t & 1) * 64;
      const uint4* src = (const uint4*)(Wt2 + (size_t)n * 128 + kh);
      #pragma unroll
      for (int i = 0; i < 8; ++i) *(uint4*)&Wt[n][kh + i * 8] = src[i];
      __syncthreads();
    }
    const float* att = ww ? att2 : att1;
    unsigned short* Hb = ww ? Hb2 : Hb1;
    float* as_ = ww ? as2 : as1;

    float4v acc[8];
    float4v z = {0.f, 0.f, 0.f, 0.f};
    #pragma unroll
    for (int nt = 0; nt < 8; ++nt) acc[nt] = z;

    #pragma unroll
    for (int ks = 0; ks < 4; ++ks) {
      short8v a = *(const short8v*)&Xt[ws + m][ks * 32 + g * 8];
      #pragma unroll
      for (int nt = 0; nt < 8; ++nt) {
        short8v b = *(const short8v*)&Wt[nt * 16 + m][ks * 32 + g * 8];
        acc[nt] = __builtin_amdgcn_mfma_f32_16x16x32_bf16(a, b, acc[nt], 0, 0, 0);
      }
    }

    // as epilogue: as[row] = sum_col acc[row][col]*att[col]
    {
      float attv[8];
      #pragma unroll
      for (int nt = 0; nt < 8; ++nt) attv[nt] = att[nt * 16 + m];
      #pragma unroll
      for (int r = 0; r < 4; ++r) {
        float s = 0.f;
        #pragma unroll
        for (int nt = 0; nt < 8; ++nt) s = fmaf(acc[nt][r], attv[nt], s);
        #pragma unroll
        for (int off = 1; off < 16; off <<= 1) s += __shfl_xor(s, off);
        if (m == 0) {
          int grow = row0 + ws + g * 4 + r;
          if (grow < M) as_[grow] = s;
        }
      }
    }

    // hs store: bf16, pack adjacent-col pairs via lane shuffle
    #pragma unroll
    for (int nt = 0; nt < 8; ++nt) {
      #pragma unroll
      for (int r = 0; r < 4; ++r) {
        float v = acc[nt][r];
        float vn = __shfl_xor(v, 1);
        if ((m & 1) == 0) {
          int grow = row0 + ws + g * 4 + r;
          if (grow < M) {
            *(unsigned*)(Hb + (size_t)grow * 128 + nt * 16 + m) = pack2(v, vn);
          }
        }
      }
    }
  }
}

// ---------- CSR build ----------
__global__ void hist4(const int* __restrict__ e0, const int* __restrict__ e1,
                      const int* __restrict__ e2, const int* __restrict__ e3,
                      int E, int* __restrict__ deg, int N) {
  int i = blockIdx.x * 256 + threadIdx.x;
  if (i >= E) return;
  int t = blockIdx.y;
  const int* ei = (t == 0) ? e0 : (t == 1) ? e1 : (t == 2) ? e2 : e3;
  atomicAdd(&deg[t * N + ei[E + i]], 1);
}

__global__ __launch_bounds__(1024) void scan4(const int* __restrict__ deg,
                                              int* __restrict__ rowptr, int N) {
  __shared__ int sums[1024];
  int t = threadIdx.x;
  int ty = blockIdx.x;
  const int* d = deg + (size_t)ty * N;
  int* rp = rowptr + (size_t)ty * (N + 1);
  int chunk = (N + 1023) / 1024;
  int lo = t * chunk;
  int hi = lo + chunk; if (hi > N) hi = N; if (lo > N) lo = N;
  int s = 0;
  for (int i = lo; i < hi; ++i) s += d[i];
  sums[t] = s;
  __syncthreads();
  for (int off = 1; off < 1024; off <<= 1) {
    int add = (t >= off) ? sums[t - off] : 0;
    __syncthreads();
    sums[t] += add;
    __syncthreads();
  }
  int run = (t == 0) ? 0 : sums[t - 1];
  for (int i = lo; i < hi; ++i) {
    rp[i] = run;
    run += d[i];
  }
  if (t == 1023) rp[N] = sums[1023];
}

__global__ void fill4(const int* __restrict__ e0, const int* __restrict__ e1,
                      const int* __restrict__ e2, const int* __restrict__ e3,
                      int E, const int* __restrict__ rowptr,
                      int* __restrict__ fill, int* __restrict__ csrc, int N) {
  int i = blockIdx.x * 256 + threadIdx.x;
  if (i >= E) return;
  int t = blockIdx.y;
  const int* ei = (t == 0) ? e0 : (t == 1) ? e1 : (t == 2) ? e2 : e3;
  int d = ei[E + i];
  int s = ei[i];
  int pos = rowptr[(size_t)t * (N + 1) + d] + atomicAdd(&fill[t * N + d], 1);
  csrc[(size_t)t * E + pos] = s;
}

// ---------- args bundle for one conv-pair ----------
struct PairArgs {
  const int* rA; const int* sA; const unsigned short* hA;
  const float* asA; const float* adA;
  const int* rB; const int* sB; const unsigned short* hB;
  const float* asB; const float* adB;
  const float* biasA; const float* biasB;
};

// ---------- interleaved dual-conv softmax agg (wave/node, 2 feats/lane) ------
// Both convs' gathers issued straight-line per batch -> 16 loads in flight.
// lsum computed from the broadcast p's on every lane (no cross-lane reduce).
__device__ __forceinline__ void agg_pair(const PairArgs& P, int n, int lane,
                                         float2& outA, float2& outB) {
  int begA = P.rA[n], endA = P.rA[n + 1];
  int begB = P.rB[n], endB = P.rB[n + 1];
  float adA = P.adA[n], adB = P.adB[n];
  float lsA = 0.f, lsB = 0.f;
  float2 aA = make_float2(0.f, 0.f), aB = make_float2(0.f, 0.f);
  int cA = begA, cB = begB;
  while (cA < endA || cB < endB) {
    int kA = cA + lane, kB = cB + lane;
    bool vA = kA < endA;
    bool vB = kB < endB;
    int sA = vA ? P.sA[kA] : 0;
    int sB = vB ? P.sB[kB] : 0;
    float eA = vA ? (P.asA[sA] + adA) : 0.f;
    float eB = vB ? (P.asB[sB] + adB) : 0.f;
    eA = eA > 0.f ? eA : NEG_SLOPE * eA;
    eB = eB > 0.f ? eB : NEG_SLOPE * eB;
    float pA = vA ? __expf(eA) : 0.f;
    float pB = vB ? __expf(eB) : 0.f;
    int cntA = endA - cA; cntA = cntA < 0 ? 0 : (cntA > 64 ? 64 : cntA);
    int cntB = endB - cB; cntB = cntB < 0 ? 0 : (cntB > 64 ? 64 : cntB);
    int cnt = cntA > cntB ? cntA : cntB;
    for (int base = 0; base < cnt; base += 8) {
      float qa0 = rl_f(pA, base + 0), qa1 = rl_f(pA, base + 1);
      float qa2 = rl_f(pA, base + 2), qa3 = rl_f(pA, base + 3);
      float qa4 = rl_f(pA, base + 4), qa5 = rl_f(pA, base + 5);
      float qa6 = rl_f(pA, base + 6), qa7 = rl_f(pA, base + 7);
      float qb0 = rl_f(pB, base + 0), qb1 = rl_f(pB, base + 1);
      float qb2 = rl_f(pB, base + 2), qb3 = rl_f(pB, base + 3);
      float qb4 = rl_f(pB, base + 4), qb5 = rl_f(pB, base + 5);
      float qb6 = rl_f(pB, base + 6), qb7 = rl_f(pB, base + 7);
      int ta0 = rl_i(sA, base + 0), ta1 = rl_i(sA, base + 1);
      int ta2 = rl_i(sA, base + 2), ta3 = rl_i(sA, base + 3);
      int ta4 = rl_i(sA, base + 4), ta5 = rl_i(sA, base + 5);
      int ta6 = rl_i(sA, base + 6), ta7 = rl_i(sA, base + 7);
      int tb0 = rl_i(sB, base + 0), tb1 = rl_i(sB, base + 1);
      int tb2 = rl_i(sB, base + 2), tb3 = rl_i(sB, base + 3);
      int tb4 = rl_i(sB, base + 4), tb5 = rl_i(sB, base + 5);
      int tb6 = rl_i(sB, base + 6), tb7 = rl_i(sB, base + 7);
      unsigned ua0 = *(const unsigned*)(P.hA + (size_t)ta0 * 128 + lane * 2);
      unsigned ua1 = *(const unsigned*)(P.hA + (size_t)ta1 * 128 + lane * 2);
      unsigned ua2 = *(const unsigned*)(P.hA + (size_t)ta2 * 128 + lane * 2);
      unsigned ua3 = *(const unsigned*)(P.hA + (size_t)ta3 * 128 + lane * 2);
      unsigned ua4 = *(const unsigned*)(P.hA + (size_t)ta4 * 128 + lane * 2);
      unsigned ua5 = *(const unsigned*)(P.hA + (size_t)ta5 * 128 + lane * 2);
      unsigned ua6 = *(const unsigned*)(P.hA + (size_t)ta6 * 128 + lane * 2);
      unsigned ua7 = *(const unsigned*)(P.hA + (size_t)ta7 * 128 + lane * 2);
      unsigned ub0 = *(const unsigned*)(P.hB + (size_t)tb0 * 128 + lane * 2);
      unsigned ub1 = *(const unsigned*)(P.hB + (size_t)tb1 * 128 + lane * 2);
      unsigned ub2 = *(const unsigned*)(P.hB + (size_t)tb2 * 128 + lane * 2);
      unsigned ub3 = *(const unsigned*)(P.hB + (size_t)tb3 * 128 + lane * 2);
      unsigned ub4 = *(const unsigned*)(P.hB + (size_t)tb4 * 128 + lane * 2);
      unsigned ub5 = *(const unsigned*)(P.hB + (size_t)tb5 * 128 + lane * 2);
      unsigned ub6 = *(const unsigned*)(P.hB + (size_t)tb6 * 128 + lane * 2);
      unsigned ub7 = *(const unsigned*)(P.hB + (size_t)tb7 * 128 + lane * 2);
      lsA += ((qa0 + qa1) + (qa2 + qa3)) + ((qa4 + qa5) + (qa6 + qa7));
      lsB += ((qb0 + qb1) + (qb2 + qb3)) + ((qb4 + qb5) + (qb6 + qb7));
      aA.x = fmaf(qa0, bflo(ua0), aA.x); aA.y = fmaf(qa0, bfhi(ua0), aA.y);
      aA.x = fmaf(qa1, bflo(ua1), aA.x); aA.y = fmaf(qa1, bfhi(ua1), aA.y);
      aA.x = fmaf(qa2, bflo(ua2), aA.x); aA.y = fmaf(qa2, bfhi(ua2), aA.y);
      aA.x = fmaf(qa3, bflo(ua3), aA.x); aA.y = fmaf(qa3, bfhi(ua3), aA.y);
      aA.x = fmaf(qa4, bflo(ua4), aA.x); aA.y = fmaf(qa4, bfhi(ua4), aA.y);
      aA.x = fmaf(qa5, bflo(ua5), aA.x); aA.y = fmaf(qa5, bfhi(ua5), aA.y);
      aA.x = fmaf(qa6, bflo(ua6), aA.x); aA.y = fmaf(qa6, bfhi(ua6), aA.y);
      aA.x = fmaf(qa7, bflo(ua7), aA.x); aA.y = fmaf(qa7, bfhi(ua7), aA.y);
      aB.x = fmaf(qb0, bflo(ub0), aB.x); aB.y = fmaf(qb0, bfhi(ub0), aB.y);
      aB.x = fmaf(qb1, bflo(ub1), aB.x); aB.y = fmaf(qb1, bfhi(ub1), aB.y);
      aB.x = fmaf(qb2, bflo(ub2), aB.x); aB.y = fmaf(qb2, bfhi(ub2), aB.y);
      aB.x = fmaf(qb3, bflo(ub3), aB.x); aB.y = fmaf(qb3, bfhi(ub3), aB.y);
      aB.x = fmaf(qb4, bflo(ub4), aB.x); aB.y = fmaf(qb4, bfhi(ub4), aB.y);
      aB.x = fmaf(qb5, bflo(ub5), aB.x); aB.y = fmaf(qb5, bfhi(ub5), aB.y);
      aB.x = fmaf(qb6, bflo(ub6), aB.x); aB.y = fmaf(qb6, bfhi(ub6), aB.y);
      aB.x = fmaf(qb7, bflo(ub7), aB.x); aB.y = fmaf(qb7, bfhi(ub7), aB.y);
    }
    cA += 64;
    cB += 64;
  }
  float invA = 1.f / fmaxf(lsA, 1e-16f);
  float invB = 1.f / fmaxf(lsB, 1e-16f);
  outA = make_float2(aA.x * invA, aA.y * invA);
  outB = make_float2(aB.x * invB, aB.y * invB);
}

// ---------- merged layer-1: both pairs in one dispatch (blockIdx.y) ----------
__global__ __launch_bounds__(256) void agg_store2(
    PairArgs P0, unsigned short* __restrict__ out0,
    PairArgs P1, unsigned short* __restrict__ out1, int N) {
  int wave = (blockIdx.x * 256 + threadIdx.x) >> 6;
  int lane = threadIdx.x & 63;
  if (wave >= N) return;
  const PairArgs& P = blockIdx.y ? P1 : P0;
  unsigned short* out = blockIdx.y ? out1 : out0;
  float2 a, b;
  agg_pair(P, wave, lane, a, b);
  float2 b1 = *(const float2*)(P.biasA + lane * 2);
  float2 b2 = *(const float2*)(P.biasB + lane * 2);
  float vx = tanhf(a.x + b.x + b1.x + b2.x);
  float vy = tanhf(a.y + b.y + b1.y + b2.y);
  *(unsigned*)(out + (size_t)wave * 128 + lane * 2) = pack2(vx, vy);
}

// ---------- merged layer-2: both pairs, pooled directly (atomic) ----------
__global__ __launch_bounds__(256) void agg_pool2(
    PairArgs P0, const int* __restrict__ batch0, float* __restrict__ pool0,
    PairArgs P1, const int* __restrict__ batch1, float* __restrict__ pool1,
    int N) {
  int wave = (blockIdx.x * 256 + threadIdx.x) >> 6;
  int lane = threadIdx.x & 63;
  if (wave >= N) return;
  const PairArgs& P = blockIdx.y ? P1 : P0;
  const int* batch = blockIdx.y ? batch1 : batch0;
  float* pool = blockIdx.y ? pool1 : pool0;
  float2 a, b;
  agg_pair(P, wave, lane, a, b);
  float2 b1 = *(const float2*)(P.biasA + lane * 2);
  float2 b2 = *(const float2*)(P.biasB + lane * 2);
  float vx = tanhf(a.x + b.x + b1.x + b2.x);
  float vy = tanhf(a.y + b.y + b1.y + b2.y);
  int bb = batch[wave];
  float* p = pool + (size_t)bb * 128 + lane * 2;
  unsafeAtomicAdd(p, vx);
  unsafeAtomicAdd(p + 1, vy);
}

// ---------- final: counts via binary search over the SORTED batch arrays ----
__device__ __forceinline__ int lower_bound_i(const int* __restrict__ a, int n,
                                             int v) {
  int lo = 0, hi = n;
  while (lo < hi) {
    int mid = (lo + hi) >> 1;
    if (a[mid] < v) lo = mid + 1; else hi = mid;
  }
  return lo;
}

__global__ void final_k(const float* __restrict__ pool_i,
                        const int* __restrict__ batch_i,
                        const float* __restrict__ pool_j,
                        const int* __restrict__ batch_j, int N,
                        const float* __restrict__ lin_w,
                        const float* __restrict__ lin_b,
                        float* __restrict__ out) {
  int b = threadIdx.x;  // 256
  float ci = (float)(lower_bound_i(batch_i, N, b + 1) -
                     lower_bound_i(batch_i, N, b));
  float cj = (float)(lower_bound_i(batch_j, N, b + 1) -
                     lower_bound_i(batch_j, N, b));
  ci = fmaxf(ci, 1.f);
  cj = fmaxf(cj, 1.f);
  float acc = 0.f;
  #pragma unroll 4
  for (int f = 0; f < 128; ++f) {
    float x = 0.5f * (pool_i[(size_t)b * 128 + f] / ci +
                      pool_j[(size_t)b * 128 + f] / cj);
    acc += x * lin_w[f];
  }
  acc += lin_b[0];
  out[b] = 1.f / (1.f + __expf(-acc));
}

extern "C" void kernel_launch(void* const* d_in, const int* in_sizes, int n_in,
                              void* d_out, int out_size, void* d_ws,
                              size_t ws_size, hipStream_t stream) {
  const float* x_i = (const float*)d_in[0];
  const float* x_j = (const float*)d_in[1];
  const int* ei_arr[4] = {(const int*)d_in[2], (const int*)d_in[3],
                          (const int*)d_in[4], (const int*)d_in[5]};  // ii,jj,ij,ji
  const int* batch_i = (const int*)d_in[6];
  const int* batch_j = (const int*)d_in[7];
  const float* Ws = (const float*)d_in[8];
  const float* Wd = (const float*)d_in[9];
  const float* att_s = (const float*)d_in[10];
  const float* att_d = (const float*)d_in[11];
  const float* bias = (const float*)d_in[12];
  const float* lin_w = (const float*)d_in[13];
  const float* lin_b = (const float*)d_in[14];
  float* out = (float*)d_out;

  const int N = in_sizes[0] / 128;   // 100000
  const int E = in_sizes[2] / 2;     // 800000
  const size_t NF = (size_t)N * 128;

  char* w = (char*)d_ws;
  auto alloc = [&](size_t bytes) {
    char* p = w;
    w += (bytes + 255) & ~(size_t)255;
    return p;
  };
  unsigned short* bufA_i = (unsigned short*)alloc(NF * 2);
  unsigned short* bufA_j = (unsigned short*)alloc(NF * 2);
  unsigned short* hsb[4];
  for (int c = 0; c < 4; ++c) hsb[c] = (unsigned short*)alloc(NF * 2);
  int* csrc = (int*)alloc((size_t)4 * E * 4);
  int* rowptr = (int*)alloc((size_t)4 * (N + 1) * 4);
  int* deg = (int*)alloc((size_t)4 * N * 4);
  int* fillc = (int*)alloc((size_t)4 * N * 4);
  float* asb[4];
  for (int c = 0; c < 4; ++c) asb[c] = (float*)alloc((size_t)N * 4);
  float* adb[4];
  for (int c = 0; c < 4; ++c) adb[c] = (float*)alloc((size_t)N * 4);
  float* wdad = (float*)alloc(8 * 128 * 4);
  unsigned short* Wst = (unsigned short*)alloc(8 * 16384 * 2);
  float* pool = (float*)alloc(2 * 256 * 128 * 4);
  float* pool_i = pool;
  float* pool_j = pool + 256 * 128;

  // ---- one-time prep ----
  w_to_bf16t<<<8, 256, 0, stream>>>(Ws, Wst);
  precompute_wa<<<8, 128, 0, stream>>>(Wd, att_d, wdad);

  // ---- CSR build (edge lists shared by both layers) ----
  hipMemsetAsync(deg, 0, (size_t)4 * N * 4, stream);
  hipMemsetAsync(fillc, 0, (size_t)4 * N * 4, stream);
  dim3 egrid((E + 255) / 256, 4);
  hist4<<<egrid, 256, 0, stream>>>(ei_arr[0], ei_arr[1], ei_arr[2], ei_arr[3],
                                   E, deg, N);
  scan4<<<4, 1024, 0, stream>>>(deg, rowptr, N);
  fill4<<<egrid, 256, 0, stream>>>(ei_arr[0], ei_arr[1], ei_arr[2], ei_arr[3],
                                   E, rowptr, fillc, csrc, N);

  hipMemsetAsync(pool, 0, 2 * 256 * 128 * 4, stream);

  const int gemm_blocks = (N + 63) / 64;
  const int nodew_blocks = (N + 3) / 4;   // one wave per node

  // conv c0 = ii (src i, dst i); c1 = jj (src j, dst j);
  // conv c2 = ij (src i, dst j); c3 = ji (src j, dst i).
  // pair0: out_i <- convs {c0, c3}; pair1: out_j <- {c1, c2}.
  for (int l = 0; l < 2; ++l) {
    const void* cur_i = (l == 0) ? (const void*)x_i : (const void*)bufA_i;
    const void* cur_j = (l == 0) ? (const void*)x_j : (const void*)bufA_j;
    const size_t L = (size_t)l * 4;

    if (l == 0) {
      gemm_dual<0><<<gemm_blocks, 256, 0, stream>>>(
          cur_i, Wst + (L + 0) * 16384, att_s + (L + 0) * 128, hsb[0], asb[0],
          Wst + (L + 2) * 16384, att_s + (L + 2) * 128, hsb[2], asb[2],
          wdad + (L + 0) * 128, wdad + (L + 3) * 128, adb[0], adb[3], N);
      gemm_dual<0><<<gemm_blocks, 256, 0, stream>>>(
          cur_j, Wst + (L + 1) * 16384, att_s + (L + 1) * 128, hsb[1], asb[1],
          Wst + (L + 3) * 16384, att_s + (L + 3) * 128, hsb[3], asb[3],
          wdad + (L + 1) * 128, wdad + (L + 2) * 128, adb[1], adb[2], N);
    } else {
      gemm_dual<1><<<gemm_blocks, 256, 0, stream>>>(
          cur_i, Wst + (L + 0) * 16384, att_s + (L + 0) * 128, hsb[0], asb[0],
          Wst + (L + 2) * 16384, att_s + (L + 2) * 128, hsb[2], asb[2],
          wdad + (L + 0) * 128, wdad + (L + 3) * 128, adb[0], adb[3], N);
      gemm_dual<1><<<gemm_blocks, 256, 0, stream>>>(
          cur_j, Wst + (L + 1) * 16384, att_s + (L + 1) * 128, hsb[1], asb[1],
          Wst + (L + 3) * 16384, att_s + (L + 3) * 128, hsb[3], asb[3],
          wdad + (L + 1) * 128, wdad + (L + 2) * 128, adb[1], adb[2], N);
    }

    PairArgs P0 = {rowptr + (size_t)0 * (N + 1), csrc + (size_t)0 * E, hsb[0],
                   asb[0], adb[0],
                   rowptr + (size_t)3 * (N + 1), csrc + (size_t)3 * E, hsb[3],
                   asb[3], adb[3],
                   bias + (L + 0) * 128, bias + (L + 3) * 128};
    PairArgs P1 = {rowptr + (size_t)1 * (N + 1), csrc + (size_t)1 * E, hsb[1],
                   asb[1], adb[1],
                   rowptr + (size_t)2 * (N + 1), csrc + (size_t)2 * E, hsb[2],
                   asb[2], adb[2],
                   bias + (L + 1) * 128, bias + (L + 2) * 128};

    dim3 agrid(nodew_blocks, 2);
    if (l == 0) {
      agg_store2<<<agrid, 256, 0, stream>>>(P0, bufA_i, P1, bufA_j, N);
    } else {
      agg_pool2<<<agrid, 256, 0, stream>>>(P0, batch_i, pool_i, P1, batch_j,
                                           pool_j, N);
    }
  }

  final_k<<<1, 256, 0, stream>>>(pool_i, batch_i, pool_j, batch_j, N, lin_w,
                                 lin_b, out);
}